// Round 15
// baseline (300.820 us; speedup 1.0000x reference)
//
#include <hip/hip_runtime.h>
#include <hip/hip_bf16.h>

#define S_LEN 2048
#define HID   4096
#define NH    32
#define NKV   8
#define HD    128

typedef __attribute__((ext_vector_type(8))) short short8v;
typedef __attribute__((ext_vector_type(4))) float floatx4;

__device__ __forceinline__ float bf2f(unsigned short u) {
  union { unsigned int u32; float f; } v; v.u32 = ((unsigned int)u) << 16; return v.f;
}
__device__ __forceinline__ unsigned short f2bf(float f) {
  union { float f; unsigned int u; } v; v.f = f;
  unsigned int u = v.u + 0x7fffu + ((v.u >> 16) & 1u);
  return (unsigned short)(u >> 16);
}
__device__ __forceinline__ unsigned int cvtpk_bf16(float lo, float hi) {
  unsigned int r;
  asm("v_cvt_pk_bf16_f32 %0, %1, %2" : "=v"(r) : "v"(lo), "v"(hi));
  return r;
}

__device__ __forceinline__ void gld_lds16(const void* g, void* l) {
  __builtin_amdgcn_global_load_lds((const __attribute__((address_space(1))) void*)g,
                                   (__attribute__((address_space(3))) void*)l, 16, 0, 0);
}

// ---------------- fused f32 -> bf16 convert, 32B-read / 16B-write per iter ----
__global__ __launch_bounds__(256) void cvt_all(const float* __restrict__ X,  const float* __restrict__ Wq,
                                               const float* __restrict__ Wk, const float* __restrict__ Wv,
                                               const float* __restrict__ Wo,
                                               unsigned short* __restrict__ Xb,  unsigned short* __restrict__ Wqb,
                                               unsigned short* __restrict__ Wkb, unsigned short* __restrict__ Wvb,
                                               unsigned short* __restrict__ Wob) {
  const int c0 = 1048576;            // X  (float8 units)
  const int c1 = c0 + 2097152;       // Wq
  const int c2 = c1 + 524288;        // Wk
  const int c3 = c2 + 524288;        // Wv
  const int c4 = c3 + 2097152;       // Wo
  int i = blockIdx.x * blockDim.x + threadIdx.x;
  int stride = gridDim.x * blockDim.x;
  for (; i < c4; i += stride) {
    const float* src; unsigned short* dst; int off;
    if (i < c0)      { src = X;  dst = Xb;  off = i; }
    else if (i < c1) { src = Wq; dst = Wqb; off = i - c0; }
    else if (i < c2) { src = Wk; dst = Wkb; off = i - c1; }
    else if (i < c3) { src = Wv; dst = Wvb; off = i - c2; }
    else             { src = Wo; dst = Wob; off = i - c3; }
    float4 v0 = ((const float4*)src)[2 * off];
    float4 v1 = ((const float4*)src)[2 * off + 1];
    union { ushort4 h[2]; uint4 u; } o;
    o.h[0].x = f2bf(v0.x); o.h[0].y = f2bf(v0.y); o.h[0].z = f2bf(v0.z); o.h[0].w = f2bf(v0.w);
    o.h[1].x = f2bf(v1.x); o.h[1].y = f2bf(v1.y); o.h[1].z = f2bf(v1.z); o.h[1].w = f2bf(v1.w);
    ((uint4*)dst)[off] = o.u;
  }
}

// =====================================================================
// gemm_qkv: 128x192 tile over CONCATENATED B = [Wq;Wk;Wv] (6144x4096).
// Grid (32,16) = 512 blocks; LDS exactly 80 KB -> 2 blocks/CU (16 waves/CU).
// 512 thr = 8 waves (2M x 4N), wave 64x48 = acc[4][3]. BK=64, 2 kh-phases.
// LDS (shorts): A: buf*8192 + kh*4096 + row*32 + slot  (2 bufs, 16 KB each)
//               B: 16384 + buf*12288 + kh*6144 + row*32 + slot (2 bufs, 24 KB)
// Staging/thread: A 1 chunk per kh (row=tid>>2, slot=tid&3); B 3 chunks
// (c = tid + j*512 -> kh=c>=768, rem=c-kh*768, row=rem>>2, slot=rem&3).
// Ledger (invariant entering ph1(t): out = 1 = A(t).kh1):
//   prologue: stage T0 [A.kh0(1), B(3), A.kh1(1)]; vmcnt(1); bar
//   ph1(t): rd kh0; stage T(t+1) (5, same order); 12 MFMA; vmcnt(5); bar
//   ph2(t): rd kh1; 12 MFMA; vmcnt(1); bar      (last tile: vmcnt(0)/skip)
// Never drains mid-loop; each wait retires exactly the next phase's data;
// buf c^1 written only after its last reader's barrier.
// =====================================================================
__global__ __launch_bounds__(512, 4) void gemm_qkv(const unsigned short* __restrict__ Xb,
                                                   const unsigned short* __restrict__ Bcat,
                                                   unsigned short* __restrict__ Qg,
                                                   unsigned short* __restrict__ Kg,
                                                   unsigned short* __restrict__ Vt) {
  __shared__ unsigned short lds[40960];   // 80 KB
  const int K = 4096;
  const int tid = threadIdx.x;
  const int w = tid >> 6, lane = tid & 63;
  const int fr = lane & 15, fq = lane >> 4;
  const int wm = w >> 2, wn = w & 3;
  const int brow = blockIdx.y * 128, bcol = blockIdx.x * 192;

  // A staging source (1 chunk/thread per kh)
  const int rA = tid >> 2, sA = tid & 3;
  const unsigned short* pA = Xb + (size_t)(brow + rA) * K + ((sA ^ ((rA >> 1) & 3)) << 3);

  // B staging sources (3 chunks/thread, full 64-k tile)
  const unsigned short* pBs[3];
#pragma unroll
  for (int j = 0; j < 3; ++j) {
    int c = tid + j * 512;
    int khj = (c >= 768) ? 1 : 0;
    int rem = c - khj * 768;
    int rowj = rem >> 2;
    int slotj = rem & 3;
    pBs[j] = Bcat + (size_t)(bcol + rowj) * K + khj * 32 +
             ((slotj ^ ((rowj >> 1) & 3)) << 3);
  }

  // ds-read offsets (within kh-region)
  const int sl = (fq ^ ((fr >> 1) & 3)) << 3;
  int aoffb[4], boffb[3];
#pragma unroll
  for (int m = 0; m < 4; ++m) aoffb[m] = (wm * 64 + m * 16 + fr) * 32 + sl;
#pragma unroll
  for (int n = 0; n < 3; ++n) boffb[n] = (wn * 48 + n * 16 + fr) * 32 + sl;

#define STG_A(buf, kh, t)                                                     \
  gld_lds16(pA + (t) * 64 + (kh) * 32, lds + (buf) * 8192 + (kh) * 4096 + w * 512)
#define STG_B(buf, t)                                                         \
  do {                                                                        \
    gld_lds16(pBs[0] + (t) * 64, lds + 16384 + (buf) * 12288 + w * 512);      \
    gld_lds16(pBs[1] + (t) * 64, lds + 16384 + (buf) * 12288 + 4096 + w * 512); \
    gld_lds16(pBs[2] + (t) * 64, lds + 16384 + (buf) * 12288 + 8192 + w * 512); \
  } while (0)

  floatx4 acc[4][3] = {};

  // prologue: T0 -> buf0 (order: A.kh0, B, A.kh1)
  STG_A(0, 0, 0);
  STG_B(0, 0);
  STG_A(0, 1, 0);
  asm volatile("s_waitcnt vmcnt(1)" ::: "memory");
  __builtin_amdgcn_s_barrier();

  const int NT = K / 64;   // 64
  for (int t = 0; t < NT; ++t) {
    const int c = t & 1;
    const unsigned short* LA = lds + c * 8192;
    const unsigned short* LB = lds + 16384 + c * 12288;
    short8v a_[4], b_[3];

    // ---- phase 1: kh0 ----
#pragma unroll
    for (int m = 0; m < 4; ++m) a_[m] = *(const short8v*)&LA[aoffb[m]];
#pragma unroll
    for (int n = 0; n < 3; ++n) b_[n] = *(const short8v*)&LB[boffb[n]];
    if (t + 1 < NT) {
      STG_A(c ^ 1, 0, t + 1);
      STG_B(c ^ 1, t + 1);
      STG_A(c ^ 1, 1, t + 1);
    }
    __builtin_amdgcn_s_setprio(1);
#pragma unroll
    for (int m = 0; m < 4; ++m)
#pragma unroll
      for (int n = 0; n < 3; ++n)
        acc[m][n] = __builtin_amdgcn_mfma_f32_16x16x32_bf16(a_[m], b_[n], acc[m][n], 0, 0, 0);
    __builtin_amdgcn_s_setprio(0);
    if (t + 1 < NT) asm volatile("s_waitcnt vmcnt(5)" ::: "memory");  // A(t).kh1 landed
    else            asm volatile("s_waitcnt vmcnt(0)" ::: "memory");
    __builtin_amdgcn_s_barrier();

    // ---- phase 2: kh1 ----
#pragma unroll
    for (int m = 0; m < 4; ++m) a_[m] = *(const short8v*)&LA[4096 + aoffb[m]];
#pragma unroll
    for (int n = 0; n < 3; ++n) b_[n] = *(const short8v*)&LB[6144 + boffb[n]];
    __builtin_amdgcn_s_setprio(1);
#pragma unroll
    for (int m = 0; m < 4; ++m)
#pragma unroll
      for (int n = 0; n < 3; ++n)
        acc[m][n] = __builtin_amdgcn_mfma_f32_16x16x32_bf16(a_[m], b_[n], acc[m][n], 0, 0, 0);
    __builtin_amdgcn_s_setprio(0);
    if (t + 1 < NT) {
      asm volatile("s_waitcnt vmcnt(1)" ::: "memory");  // T(t+1).kh0 + B landed
      __builtin_amdgcn_s_barrier();
    }
  }
#undef STG_A
#undef STG_B

  // ---- epilogue: per-frag routing (boundaries 4096/5120 are 16-aligned) ----
  const int r0 = brow + wm * 64 + fq * 4;
#pragma unroll
  for (int m = 0; m < 4; ++m)
#pragma unroll
    for (int n = 0; n < 3; ++n) {
      const int bc = bcol + wn * 48 + n * 16;   // frag base col (wave-uniform)
      if (bc < 4096) {
#pragma unroll
        for (int r = 0; r < 4; ++r)
          Qg[(size_t)(r0 + m * 16 + r) * HID + bc + fr] = f2bf(acc[m][n][r]);
      } else if (bc < 5120) {
#pragma unroll
        for (int r = 0; r < 4; ++r)
          Kg[(size_t)(r0 + m * 16 + r) * 1024 + bc - 4096 + fr] = f2bf(acc[m][n][r]);
      } else {
        ushort4 pk;
        pk.x = f2bf(acc[m][n][0]); pk.y = f2bf(acc[m][n][1]);
        pk.z = f2bf(acc[m][n][2]); pk.w = f2bf(acc[m][n][3]);
        *(ushort4*)&Vt[(size_t)(bc - 5120 + fr) * S_LEN + (r0 + m * 16)] = pk;
      }
    }
}

// =====================================================================
// gemm_o: 256x128 / BK=64 / 2-phase / raw-barrier / counted-vmcnt (r10, proven).
// =====================================================================
__global__ __launch_bounds__(512, 2) void gemm_o(const unsigned short* __restrict__ Ao,
                                                 const unsigned short* __restrict__ Wob,
                                                 float* __restrict__ Out) {
  __shared__ unsigned short lds[2 * 24576];   // 96 KB
  const int K = 4096;
  const int tid = threadIdx.x;
  const int w = tid >> 6, lane = tid & 63;
  const int fr = lane & 15, fq = lane >> 4;
  const int wm = w >> 1, wn = w & 1;
  const int brow = blockIdx.y * 256, bcol = blockIdx.x * 128;

  const int rA = tid >> 2;
  const int sA = ((tid & 3) ^ ((rA >> 1) & 3)) << 3;
  const unsigned short* pA0 = Ao  + (size_t)(brow + rA) * K + sA;
  const unsigned short* pA1 = Ao  + (size_t)(brow + 128 + rA) * K + sA;
  const unsigned short* pB0 = Wob + (size_t)(bcol + rA) * K + sA;

  const int sl = (fq ^ ((fr >> 1) & 3)) << 3;
  int aoff[4], boff[4];
#pragma unroll
  for (int m = 0; m < 4; ++m) aoff[m] = (wm * 64 + m * 16 + fr) * 32 + sl;
#pragma unroll
  for (int n = 0; n < 4; ++n) boff[n] = 16384 + (wn * 64 + n * 16 + fr) * 32 + sl;

  floatx4 acc[4][4] = {};

#define STG_KH(buf, kh, t)                                                       \
  do {                                                                           \
    const int ko_ = (t) * 64 + (kh) * 32;                                        \
    gld_lds16(pA0 + ko_, lds + (buf) * 24576 + (kh) * 8192 + w * 512);           \
    gld_lds16(pA1 + ko_, lds + (buf) * 24576 + (kh) * 8192 + 4096 + w * 512);    \
    gld_lds16(pB0 + ko_, lds + (buf) * 24576 + 16384 + (kh) * 4096 + w * 512);   \
  } while (0)

  STG_KH(0, 0, 0);
  STG_KH(0, 1, 0);
  STG_KH(1, 0, 1);
  asm volatile("s_waitcnt vmcnt(6)" ::: "memory");
  __builtin_amdgcn_s_barrier();

  const int NT = K / 64;   // 64
  for (int t = 0; t < NT; ++t) {
    const int c = t & 1;
    const unsigned short* Lc = lds + c * 24576;
    short8v a_[4], b_[4];

#pragma unroll
    for (int m = 0; m < 4; ++m) a_[m] = *(const short8v*)&Lc[aoff[m]];
#pragma unroll
    for (int n = 0; n < 4; ++n) b_[n] = *(const short8v*)&Lc[boff[n]];
    if (t + 1 < NT) STG_KH(c ^ 1, 1, t + 1);
    __builtin_amdgcn_s_setprio(1);
#pragma unroll
    for (int m = 0; m < 4; ++m)
#pragma unroll
      for (int n = 0; n < 4; ++n)
        acc[m][n] = __builtin_amdgcn_mfma_f32_16x16x32_bf16(a_[m], b_[n], acc[m][n], 0, 0, 0);
    __builtin_amdgcn_s_setprio(0);
    if (t + 1 < NT) asm volatile("s_waitcnt vmcnt(6)" ::: "memory");
    else            asm volatile("s_waitcnt vmcnt(0)" ::: "memory");
    __builtin_amdgcn_s_barrier();

#pragma unroll
    for (int m = 0; m < 4; ++m) a_[m] = *(const short8v*)&Lc[8192 + aoff[m]];
#pragma unroll
    for (int n = 0; n < 4; ++n) b_[n] = *(const short8v*)&Lc[4096 + boff[n]];
    if (t + 2 < NT) STG_KH(c, 0, t + 2);
    __builtin_amdgcn_s_setprio(1);
#pragma unroll
    for (int m = 0; m < 4; ++m)
#pragma unroll
      for (int n = 0; n < 4; ++n)
        acc[m][n] = __builtin_amdgcn_mfma_f32_16x16x32_bf16(a_[m], b_[n], acc[m][n], 0, 0, 0);
    __builtin_amdgcn_s_setprio(0);
    if (t + 2 < NT)      asm volatile("s_waitcnt vmcnt(6)" ::: "memory");
    else if (t + 1 < NT) asm volatile("s_waitcnt vmcnt(3)" ::: "memory");
    else                 asm volatile("s_waitcnt vmcnt(0)" ::: "memory");
    __builtin_amdgcn_s_barrier();
  }
#undef STG_KH

  const int r0 = brow + wm * 64 + fq * 4;
  const int c0 = bcol + wn * 64 + fr;
#pragma unroll
  for (int m = 0; m < 4; ++m)
#pragma unroll
    for (int n = 0; n < 4; ++n)
#pragma unroll
      for (int r = 0; r < 4; ++r)
        Out[(size_t)(r0 + m * 16 + r) * HID + c0 + n * 16] = acc[m][n][r];
}

// ---------------- K RoPE: INTERLEAVED layout (pair results at 2j, 2j+1) ------
__global__ __launch_bounds__(256) void rope_k(const unsigned short* __restrict__ In,
                                              const float* __restrict__ cosT,
                                              const float* __restrict__ sinT,
                                              unsigned short* __restrict__ Out) {
  int idx = blockIdx.x * 256 + threadIdx.x;
  int j = idx & 63;
  int s = (idx >> 6) & (S_LEN - 1);
  int h = idx >> 17;
  unsigned int pr = *(const unsigned int*)(In + (size_t)s * (NKV * HD) + h * HD + 2 * j);
  float k1 = bf2f((unsigned short)(pr & 0xffffu));
  float k2 = bf2f((unsigned short)(pr >> 16));
  float c = cosT[s * 64 + j], sn = sinT[s * 64 + j];
  unsigned int pk = (unsigned int)f2bf(k1 * c - k2 * sn) |
                    ((unsigned int)f2bf(k2 * c + k1 * sn) << 16);
  *(unsigned int*)(Out + ((size_t)h * S_LEN + s) * HD + 2 * j) = pk;
}

// ---------------- Flash attention: 8-wave blocks, shared K/V tile (r12, proven)
__global__ __launch_bounds__(512, 4) void attn_fwd(const unsigned short* __restrict__ Qg,
                                                   const float* __restrict__ cosT,
                                                   const float* __restrict__ sinT,
                                                   const unsigned short* __restrict__ Kr,
                                                   const unsigned short* __restrict__ Vt,
                                                   unsigned short* __restrict__ Ao) {
  __shared__ unsigned short Kl[2][64 * 128];   // [kv][128], swizzled (cb ^ (row&7)<<4)
  __shared__ unsigned short Vl[2][128 * 64];   // [d][kv], swizzled
  const int id = blockIdx.x;
  const int xcd = id & 7, rr = id >> 3;
  const int qt = 15 - (rr >> 2);               // heavy first
  const int h  = xcd * 4 + (rr & 3);           // XCD c <-> kv-head c
  const int hk = h >> 2;
  const int qb = qt * 128;
  const int tid = threadIdx.x, w = tid >> 6, lane = tid & 63;
  const int fr = lane & 15, fq = lane >> 4;

  short8v aq[4];
  {
    const int s_row = qb + w * 16 + fr;
    const unsigned short* qp = Qg + (size_t)s_row * HID + h * HD + fq * 8;
    const float* cb = cosT + s_row * 64;
    const float* sb = sinT + s_row * 64;
    const float SC = 0.12751744f;   // log2(e)/sqrt(128)
#pragma unroll
    for (int ks = 0; ks < 4; ++ks) {
      short8v raw = *(const short8v*)(qp + ks * 32);
      short8v ov;
#pragma unroll
      for (int e = 0; e < 4; ++e) {
        float q1 = bf2f((unsigned short)raw[2 * e]);
        float q2 = bf2f((unsigned short)raw[2 * e + 1]);
        int j = ks * 16 + fq * 4 + e;
        float c = cb[j], sn = sb[j];
        ov[2 * e]     = (short)f2bf(SC * (q1 * c - q2 * sn));
        ov[2 * e + 1] = (short)f2bf(SC * (q2 * c + q1 * sn));
      }
      aq[ks] = ov;
    }
  }

  const int kcb = ((tid & 15) * 16) ^ (((tid >> 4) & 7) << 4);
  const unsigned short* pK0 = Kr + ((size_t)hk * S_LEN + (tid >> 4)) * HD + (kcb >> 1);
  const int vcb = ((tid & 7) * 16) ^ (((tid >> 3) & 7) << 4);
  const unsigned short* pV0 = Vt + ((size_t)hk * HD + (tid >> 3)) * S_LEN + (vcb >> 1);

  const int hsel = fq >> 1;
  const int srcA = fr + ((2 * (fq & 1)) << 4);
  const int srcB = fr + ((2 * (fq & 1) + 1) << 4);

  float l_acc = 0.f;
  floatx4 o[8] = {};

#define STAGE(buf, t)                                                           \
  do {                                                                          \
    const unsigned short* pk_ = pK0 + (size_t)(t) * 64 * HD;                    \
    const unsigned short* pv_ = pV0 + (t) * 64;                                 \
    _Pragma("unroll")                                                           \
    for (int j = 0; j < 2; ++j)                                                 \
      gld_lds16(pk_ + (size_t)j * 32 * HD, &Kl[buf][j * 4096 + w * 512]);       \
    _Pragma("unroll")                                                           \
    for (int j = 0; j < 2; ++j)                                                 \
      gld_lds16(pv_ + (size_t)j * 64 * S_LEN, &Vl[buf][j * 4096 + w * 512]);    \
  } while (0)

  STAGE(0, 0);
  asm volatile("s_waitcnt vmcnt(0)" ::: "memory");
  __syncthreads();

  const int nt = 2 * qt + 2;
  int cur = 0;
  for (int t = 0; t < nt; ++t) {
    const int kv0 = t * 64;
    if (t + 1 < nt) STAGE(cur ^ 1, t + 1);

    floatx4 St[4] = {};
    const unsigned short* Kc = &Kl[cur][0];
    const unsigned short* Vc = &Vl[cur][0];
    __builtin_amdgcn_s_setprio(1);
#pragma unroll
    for (int ks = 0; ks < 4; ++ks) {
#pragma unroll
      for (int n = 0; n < 4; ++n) {
        int row = n * 16 + fr;
        int cb = (ks * 64 + fq * 16) ^ ((row & 7) << 4);
        short8v kf = *(const short8v*)&Kc[row * 128 + (cb >> 1)];
        St[n] = __builtin_amdgcn_mfma_f32_16x16x32_bf16(kf, aq[ks], St[n], 0, 0, 0);
      }
    }
    __builtin_amdgcn_s_setprio(0);

    if (t >= 2 * qt) {
#pragma unroll
      for (int n = 0; n < 4; ++n) {
#pragma unroll
        for (int r = 0; r < 4; ++r) {
          int kvg = kv0 + n * 16 + fq * 4 + r;
          if (kvg > qb + w * 16 + fr) St[n][r] = -1e30f;
        }
      }
    }

    unsigned int pk[4][2];
#pragma unroll
    for (int n = 0; n < 4; ++n) {
      float p0 = exp2f(St[n][0]);
      float p1 = exp2f(St[n][1]);
      float p2 = exp2f(St[n][2]);
      float p3 = exp2f(St[n][3]);
      l_acc += (p0 + p1) + (p2 + p3);
      pk[n][0] = cvtpk_bf16(p0, p1);
      pk[n][1] = cvtpk_bf16(p2, p3);
    }

    short8v pa[2];
#pragma unroll
    for (int ks = 0; ks < 2; ++ks) {
      unsigned int v0a = __shfl(pk[2 * ks][0], srcA), v0b = __shfl(pk[2 * ks + 1][0], srcA);
      unsigned int v1a = __shfl(pk[2 * ks][1], srcA), v1b = __shfl(pk[2 * ks + 1][1], srcA);
      unsigned int v2a = __shfl(pk[2 * ks][0], srcB), v2b = __shfl(pk[2 * ks + 1][0], srcB);
      unsigned int v3a = __shfl(pk[2 * ks][1], srcB), v3b = __shfl(pk[2 * ks + 1][1], srcB);
      uint4 u;
      u.x = hsel ? v0b : v0a;
      u.y = hsel ? v1b : v1a;
      u.z = hsel ? v2b : v2a;
      u.w = hsel ? v3b : v3a;
      pa[ks] = *(short8v*)&u;
    }

    __builtin_amdgcn_s_setprio(1);
#pragma unroll
    for (int nf = 0; nf < 8; ++nf) {
#pragma unroll
      for (int ks = 0; ks < 2; ++ks) {
        int row = nf * 16 + fr;
        int cb = (ks * 64 + fq * 16) ^ ((row & 7) << 4);
        short8v bv = *(const short8v*)&Vc[row * 64 + (cb >> 1)];
        o[nf] = __builtin_amdgcn_mfma_f32_16x16x32_bf16(pa[ks], bv, o[nf], 0, 0, 0);
      }
    }
    __builtin_amdgcn_s_setprio(0);

    if (t + 1 < nt) {
      asm volatile("s_waitcnt vmcnt(0)" ::: "memory");
      __syncthreads();
      cur ^= 1;
    }
  }
#undef STAGE

  float L = l_acc;
  L += __shfl_xor(L, 16);
  L += __shfl_xor(L, 32);
  float rinv[4];
#pragma unroll
  for (int r = 0; r < 4; ++r) rinv[r] = 1.0f / __shfl(L, fq * 4 + r);

  unsigned short* aop = Ao + (size_t)(qb + w * 16 + fq * 4) * HID + h * HD + fr;
#pragma unroll
  for (int nf = 0; nf < 8; ++nf)
#pragma unroll
    for (int r = 0; r < 4; ++r)
      aop[(size_t)r * HID + nf * 16] = f2bf(o[nf][r] * rinv[r]);
}

// ---------------- launch ----------------
extern "C" void kernel_launch(void* const* d_in, const int* in_sizes, int n_in,
                              void* d_out, int out_size, void* d_ws, size_t ws_size,
                              hipStream_t stream) {
  (void)in_sizes; (void)n_in; (void)out_size; (void)ws_size;
  const float* X    = (const float*)d_in[0];
  const float* cosT = (const float*)d_in[3];
  const float* sinT = (const float*)d_in[4];
  const float* Wq   = (const float*)d_in[5];
  const float* Wk   = (const float*)d_in[6];
  const float* Wv   = (const float*)d_in[7];
  const float* Wo   = (const float*)d_in[8];

  char* ws = (char*)d_ws;
  size_t off = 0;
  auto alloc = [&](size_t bytes) { char* p = ws + off; off += (bytes + 255) & ~(size_t)255; return p; };
  unsigned short* Xb  = (unsigned short*)alloc((size_t)S_LEN * HID * 2);
  // Wqb/Wkb/Wvb are contiguous -> concatenated B matrix [Wq;Wk;Wv] (6144x4096)
  unsigned short* Wqb = (unsigned short*)alloc((size_t)HID * HID * 2);
  unsigned short* Wkb = (unsigned short*)alloc((size_t)1024 * HID * 2);
  unsigned short* Wvb = (unsigned short*)alloc((size_t)1024 * HID * 2);
  unsigned short* Wob = (unsigned short*)alloc((size_t)HID * HID * 2);
  unsigned short* Qg  = (unsigned short*)alloc((size_t)S_LEN * HID * 2);
  unsigned short* Kg  = (unsigned short*)alloc((size_t)S_LEN * 1024 * 2);
  unsigned short* Vt  = (unsigned short*)alloc((size_t)1024 * S_LEN * 2);
  unsigned short* Kr = Wqb;      // alias: Wqb dead after gemm_qkv
  unsigned short* Ao = Xb;       // alias: Xb dead after gemm_qkv

  cvt_all<<<2048, 256, 0, stream>>>(X, Wq, Wk, Wv, Wo, Xb, Wqb, Wkb, Wvb, Wob);
  gemm_qkv<<<dim3(32, 16), 512, 0, stream>>>(Xb, Wqb, Qg, Kg, Vt);
  rope_k<<<(NKV * S_LEN * 64) / 256, 256, 0, stream>>>(Kg, cosT, sinT, Kr);
  attn_fwd<<<512, 512, 0, stream>>>(Qg, cosT, sinT, Kr, Vt, Ao);
  gemm_o<<<dim3(32, 8), 512, 0, stream>>>(Ao, Wob, (float*)d_out);
}

// Round 16
// 293.918 us; speedup vs baseline: 1.0235x; 1.0235x over previous
//
#include <hip/hip_runtime.h>
#include <hip/hip_bf16.h>

#define S_LEN 2048
#define HID   4096
#define NH    32
#define NKV   8
#define HD    128

typedef __attribute__((ext_vector_type(8))) short short8v;
typedef __attribute__((ext_vector_type(4))) float floatx4;

__device__ __forceinline__ float bf2f(unsigned short u) {
  union { unsigned int u32; float f; } v; v.u32 = ((unsigned int)u) << 16; return v.f;
}
__device__ __forceinline__ unsigned short f2bf(float f) {
  union { float f; unsigned int u; } v; v.f = f;
  unsigned int u = v.u + 0x7fffu + ((v.u >> 16) & 1u);
  return (unsigned short)(u >> 16);
}
__device__ __forceinline__ unsigned int cvtpk_bf16(float lo, float hi) {
  unsigned int r;
  asm("v_cvt_pk_bf16_f32 %0, %1, %2" : "=v"(r) : "v"(lo), "v"(hi));
  return r;
}

__device__ __forceinline__ void gld_lds16(const void* g, void* l) {
  __builtin_amdgcn_global_load_lds((const __attribute__((address_space(1))) void*)g,
                                   (__attribute__((address_space(3))) void*)l, 16, 0, 0);
}

// ---------------- fused f32 -> bf16 convert, 32B-read / 16B-write per iter ----
__global__ __launch_bounds__(256) void cvt_all(const float* __restrict__ X,  const float* __restrict__ Wq,
                                               const float* __restrict__ Wk, const float* __restrict__ Wv,
                                               const float* __restrict__ Wo,
                                               unsigned short* __restrict__ Xb,  unsigned short* __restrict__ Wqb,
                                               unsigned short* __restrict__ Wkb, unsigned short* __restrict__ Wvb,
                                               unsigned short* __restrict__ Wob) {
  const int c0 = 1048576;            // X  (float8 units)
  const int c1 = c0 + 2097152;       // Wq
  const int c2 = c1 + 524288;        // Wk
  const int c3 = c2 + 524288;        // Wv
  const int c4 = c3 + 2097152;       // Wo
  int i = blockIdx.x * blockDim.x + threadIdx.x;
  int stride = gridDim.x * blockDim.x;
  for (; i < c4; i += stride) {
    const float* src; unsigned short* dst; int off;
    if (i < c0)      { src = X;  dst = Xb;  off = i; }
    else if (i < c1) { src = Wq; dst = Wqb; off = i - c0; }
    else if (i < c2) { src = Wk; dst = Wkb; off = i - c1; }
    else if (i < c3) { src = Wv; dst = Wvb; off = i - c2; }
    else             { src = Wo; dst = Wob; off = i - c3; }
    float4 v0 = ((const float4*)src)[2 * off];
    float4 v1 = ((const float4*)src)[2 * off + 1];
    union { ushort4 h[2]; uint4 u; } o;
    o.h[0].x = f2bf(v0.x); o.h[0].y = f2bf(v0.y); o.h[0].z = f2bf(v0.z); o.h[0].w = f2bf(v0.w);
    o.h[1].x = f2bf(v1.x); o.h[1].y = f2bf(v1.y); o.h[1].z = f2bf(v1.z); o.h[1].w = f2bf(v1.w);
    ((uint4*)dst)[off] = o.u;
  }
}

// =====================================================================
// gemm_qkv: 256x192 tile over CONCATENATED B = [Wq;Wk;Wv] (6144x4096).
// Grid (32,8) = 256 equal blocks = perfect CU fill (r14 proven: 110.7 us).
// 512 thr = 8 waves (2M x 4N), wave 128x48 = acc[8][3]. BK=64, 2 kh-phases.
// LDS: A 2 x 32 KB + B 3 x 24 KB = 136 KB. Counted-vmcnt ledger as r14.
// Epilogue: per-frag routing; K frags (bc in [4096,5120)) get FUSED
// INTERLEAVED ROPE (pair = lane fr^1 -> shfl_xor(acc,1)) written to Kr.
// =====================================================================
__global__ __launch_bounds__(512, 2) void gemm_qkv(const unsigned short* __restrict__ Xb,
                                                   const unsigned short* __restrict__ Bcat,
                                                   const float* __restrict__ cosT,
                                                   const float* __restrict__ sinT,
                                                   unsigned short* __restrict__ Qg,
                                                   unsigned short* __restrict__ Kr,
                                                   unsigned short* __restrict__ Vt) {
  __shared__ unsigned short lds[2 * 16384 + 3 * 12288];   // 136 KB
  const int K = 4096;
  const int tid = threadIdx.x;
  const int w = tid >> 6, lane = tid & 63;
  const int fr = lane & 15, fq = lane >> 4;
  const int wm = w >> 2, wn = w & 3;
  const int brow = blockIdx.y * 256, bcol = blockIdx.x * 192;

  const int r0s = w * 32 + (lane >> 2);
  const int r1s = r0s + 16;
  const int sl0 = ((lane & 3) ^ ((r0s >> 1) & 3)) << 3;
  const int sl1 = ((lane & 3) ^ ((r1s >> 1) & 3)) << 3;
  const unsigned short* pAs0 = Xb + (size_t)(brow + r0s) * K + sl0;
  const unsigned short* pAs1 = Xb + (size_t)(brow + r1s) * K + sl1;

  const unsigned short* pBs[3];
#pragma unroll
  for (int j = 0; j < 3; ++j) {
    int c = tid + j * 512;
    int khj = (c >= 768) ? 1 : 0;
    int rowj = (c - khj * 768) >> 2;
    int slotj = c & 3;
    pBs[j] = Bcat + (size_t)(bcol + rowj) * K + khj * 32 +
             ((slotj ^ ((rowj >> 1) & 3)) << 3);
  }

  const int sl = (fq ^ ((fr >> 1) & 3)) << 3;
  int aoffb[8], boffb[3];
#pragma unroll
  for (int m = 0; m < 8; ++m) aoffb[m] = (wm * 128 + m * 16 + fr) * 32 + sl;
#pragma unroll
  for (int n = 0; n < 3; ++n) boffb[n] = (wn * 48 + n * 16 + fr) * 32 + sl;

#define STG_A(buf, kh, t)                                                     \
  do {                                                                        \
    const int ko_ = (t) * 64 + (kh) * 32;                                     \
    gld_lds16(pAs0 + ko_, lds + (buf) * 16384 + (kh) * 8192 + w * 1024);      \
    gld_lds16(pAs1 + ko_, lds + (buf) * 16384 + (kh) * 8192 + w * 1024 + 512);\
  } while (0)
#define STG_B(bb, t)                                                          \
  do {                                                                        \
    const int ko_ = (t) * 64;                                                 \
    gld_lds16(pBs[0] + ko_, lds + 32768 + (bb) * 12288 + w * 512);            \
    gld_lds16(pBs[1] + ko_, lds + 32768 + (bb) * 12288 + 4096 + w * 512);     \
    gld_lds16(pBs[2] + ko_, lds + 32768 + (bb) * 12288 + 8192 + w * 512);     \
  } while (0)

  floatx4 acc[8][3] = {};

  STG_A(0, 0, 0); STG_A(0, 1, 0); STG_B(0, 0);
  STG_A(1, 0, 1);                 STG_B(1, 1);
  asm volatile("s_waitcnt vmcnt(5)" ::: "memory");
  __builtin_amdgcn_s_barrier();

  const int NT = K / 64;   // 64
  for (int t = 0; t < NT; ++t) {
    const int c = t & 1;
    const int bb = t % 3;
    const unsigned short* LA = lds + c * 16384;
    const unsigned short* LB = lds + 32768 + bb * 12288;
    short8v a_[8], b_[3];

    // ---- phase 1: kh0 ----
#pragma unroll
    for (int m = 0; m < 8; ++m) a_[m] = *(const short8v*)&LA[aoffb[m]];
#pragma unroll
    for (int n = 0; n < 3; ++n) b_[n] = *(const short8v*)&LB[boffb[n]];
    if (t + 1 < NT) STG_A(c ^ 1, 1, t + 1);
    if (t + 2 < NT) STG_B((bb + 2) % 3, t + 2);
    __builtin_amdgcn_s_setprio(1);
#pragma unroll
    for (int m = 0; m < 8; ++m)
#pragma unroll
      for (int n = 0; n < 3; ++n)
        acc[m][n] = __builtin_amdgcn_mfma_f32_16x16x32_bf16(a_[m], b_[n], acc[m][n], 0, 0, 0);
    __builtin_amdgcn_s_setprio(0);
    if (t + 2 < NT)      asm volatile("s_waitcnt vmcnt(10)" ::: "memory");
    else if (t + 1 < NT) asm volatile("s_waitcnt vmcnt(7)" ::: "memory");
    else                 asm volatile("s_waitcnt vmcnt(0)" ::: "memory");
    __builtin_amdgcn_s_barrier();

    // ---- phase 2: kh1 ----
#pragma unroll
    for (int m = 0; m < 8; ++m) a_[m] = *(const short8v*)&LA[8192 + aoffb[m]];
#pragma unroll
    for (int n = 0; n < 3; ++n) b_[n] = *(const short8v*)&LB[6144 + boffb[n]];
    if (t + 2 < NT) STG_A(c, 0, t + 2);
    __builtin_amdgcn_s_setprio(1);
#pragma unroll
    for (int m = 0; m < 8; ++m)
#pragma unroll
      for (int n = 0; n < 3; ++n)
        acc[m][n] = __builtin_amdgcn_mfma_f32_16x16x32_bf16(a_[m], b_[n], acc[m][n], 0, 0, 0);
    __builtin_amdgcn_s_setprio(0);
    if (t + 2 < NT)      asm volatile("s_waitcnt vmcnt(7)" ::: "memory");
    else if (t + 1 < NT) asm volatile("s_waitcnt vmcnt(2)" ::: "memory");
    else                 asm volatile("s_waitcnt vmcnt(0)" ::: "memory");
    __builtin_amdgcn_s_barrier();
  }
#undef STG_A
#undef STG_B

  // ---- epilogue: per-frag routing; K frags get fused interleaved rope ----
  const int r0 = brow + wm * 128 + fq * 4;
#pragma unroll
  for (int m = 0; m < 8; ++m)
#pragma unroll
    for (int n = 0; n < 3; ++n) {
      const int bc = bcol + wn * 48 + n * 16;   // frag base col (wave-uniform)
      if (bc < 4096) {
#pragma unroll
        for (int r = 0; r < 4; ++r)
          Qg[(size_t)(r0 + m * 16 + r) * HID + bc + fr] = f2bf(acc[m][n][r]);
      } else if (bc < 5120) {
        // K: interleaved rope fused. colk in [0,1024), pair = lane fr^1.
        const int colk = bc - 4096 + fr;
        const int d = colk & 127;
        const int j = d >> 1;
        unsigned short* kd = Kr + (size_t)(colk >> 7) * (S_LEN * HD) + d;
#pragma unroll
        for (int r = 0; r < 4; ++r) {
          const int row = r0 + m * 16 + r;
          float a = acc[m][n][r];
          float p = __shfl_xor(a, 1);
          float cc = cosT[row * 64 + j], ss = sinT[row * 64 + j];
          float val = (d & 1) ? (a * cc + p * ss) : (a * cc - p * ss);
          kd[(size_t)row * HD] = f2bf(val);
        }
      } else {
        ushort4 pk;
        pk.x = f2bf(acc[m][n][0]); pk.y = f2bf(acc[m][n][1]);
        pk.z = f2bf(acc[m][n][2]); pk.w = f2bf(acc[m][n][3]);
        *(ushort4*)&Vt[(size_t)(bc - 5120 + fr) * S_LEN + (r0 + m * 16)] = pk;
      }
    }
}

// =====================================================================
// gemm_o: 256x128 / BK=64 / 2-phase / raw-barrier / counted-vmcnt (r10, proven).
// =====================================================================
__global__ __launch_bounds__(512, 2) void gemm_o(const unsigned short* __restrict__ Ao,
                                                 const unsigned short* __restrict__ Wob,
                                                 float* __restrict__ Out) {
  __shared__ unsigned short lds[2 * 24576];   // 96 KB
  const int K = 4096;
  const int tid = threadIdx.x;
  const int w = tid >> 6, lane = tid & 63;
  const int fr = lane & 15, fq = lane >> 4;
  const int wm = w >> 1, wn = w & 1;
  const int brow = blockIdx.y * 256, bcol = blockIdx.x * 128;

  const int rA = tid >> 2;
  const int sA = ((tid & 3) ^ ((rA >> 1) & 3)) << 3;
  const unsigned short* pA0 = Ao  + (size_t)(brow + rA) * K + sA;
  const unsigned short* pA1 = Ao  + (size_t)(brow + 128 + rA) * K + sA;
  const unsigned short* pB0 = Wob + (size_t)(bcol + rA) * K + sA;

  const int sl = (fq ^ ((fr >> 1) & 3)) << 3;
  int aoff[4], boff[4];
#pragma unroll
  for (int m = 0; m < 4; ++m) aoff[m] = (wm * 64 + m * 16 + fr) * 32 + sl;
#pragma unroll
  for (int n = 0; n < 4; ++n) boff[n] = 16384 + (wn * 64 + n * 16 + fr) * 32 + sl;

  floatx4 acc[4][4] = {};

#define STG_KH(buf, kh, t)                                                       \
  do {                                                                           \
    const int ko_ = (t) * 64 + (kh) * 32;                                        \
    gld_lds16(pA0 + ko_, lds + (buf) * 24576 + (kh) * 8192 + w * 512);           \
    gld_lds16(pA1 + ko_, lds + (buf) * 24576 + (kh) * 8192 + 4096 + w * 512);    \
    gld_lds16(pB0 + ko_, lds + (buf) * 24576 + 16384 + (kh) * 4096 + w * 512);   \
  } while (0)

  STG_KH(0, 0, 0);
  STG_KH(0, 1, 0);
  STG_KH(1, 0, 1);
  asm volatile("s_waitcnt vmcnt(6)" ::: "memory");
  __builtin_amdgcn_s_barrier();

  const int NT = K / 64;   // 64
  for (int t = 0; t < NT; ++t) {
    const int c = t & 1;
    const unsigned short* Lc = lds + c * 24576;
    short8v a_[4], b_[4];

#pragma unroll
    for (int m = 0; m < 4; ++m) a_[m] = *(const short8v*)&Lc[aoff[m]];
#pragma unroll
    for (int n = 0; n < 4; ++n) b_[n] = *(const short8v*)&Lc[boff[n]];
    if (t + 1 < NT) STG_KH(c ^ 1, 1, t + 1);
    __builtin_amdgcn_s_setprio(1);
#pragma unroll
    for (int m = 0; m < 4; ++m)
#pragma unroll
      for (int n = 0; n < 4; ++n)
        acc[m][n] = __builtin_amdgcn_mfma_f32_16x16x32_bf16(a_[m], b_[n], acc[m][n], 0, 0, 0);
    __builtin_amdgcn_s_setprio(0);
    if (t + 1 < NT) asm volatile("s_waitcnt vmcnt(6)" ::: "memory");
    else            asm volatile("s_waitcnt vmcnt(0)" ::: "memory");
    __builtin_amdgcn_s_barrier();

#pragma unroll
    for (int m = 0; m < 4; ++m) a_[m] = *(const short8v*)&Lc[8192 + aoff[m]];
#pragma unroll
    for (int n = 0; n < 4; ++n) b_[n] = *(const short8v*)&Lc[4096 + boff[n]];
    if (t + 2 < NT) STG_KH(c, 0, t + 2);
    __builtin_amdgcn_s_setprio(1);
#pragma unroll
    for (int m = 0; m < 4; ++m)
#pragma unroll
      for (int n = 0; n < 4; ++n)
        acc[m][n] = __builtin_amdgcn_mfma_f32_16x16x32_bf16(a_[m], b_[n], acc[m][n], 0, 0, 0);
    __builtin_amdgcn_s_setprio(0);
    if (t + 2 < NT)      asm volatile("s_waitcnt vmcnt(6)" ::: "memory");
    else if (t + 1 < NT) asm volatile("s_waitcnt vmcnt(3)" ::: "memory");
    else                 asm volatile("s_waitcnt vmcnt(0)" ::: "memory");
    __builtin_amdgcn_s_barrier();
  }
#undef STG_KH

  const int r0 = brow + wm * 64 + fq * 4;
  const int c0 = bcol + wn * 64 + fr;
#pragma unroll
  for (int m = 0; m < 4; ++m)
#pragma unroll
    for (int n = 0; n < 4; ++n)
#pragma unroll
      for (int r = 0; r < 4; ++r)
        Out[(size_t)(r0 + m * 16 + r) * HID + c0 + n * 16] = acc[m][n][r];
}

// ---------------- Flash attention: 8-wave blocks, shared K/V tile (r12, proven)
__global__ __launch_bounds__(512, 4) void attn_fwd(const unsigned short* __restrict__ Qg,
                                                   const float* __restrict__ cosT,
                                                   const float* __restrict__ sinT,
                                                   const unsigned short* __restrict__ Kr,
                                                   const unsigned short* __restrict__ Vt,
                                                   unsigned short* __restrict__ Ao) {
  __shared__ unsigned short Kl[2][64 * 128];   // [kv][128], swizzled (cb ^ (row&7)<<4)
  __shared__ unsigned short Vl[2][128 * 64];   // [d][kv], swizzled
  const int id = blockIdx.x;
  const int xcd = id & 7, rr = id >> 3;
  const int qt = 15 - (rr >> 2);               // heavy first
  const int h  = xcd * 4 + (rr & 3);           // XCD c <-> kv-head c
  const int hk = h >> 2;
  const int qb = qt * 128;
  const int tid = threadIdx.x, w = tid >> 6, lane = tid & 63;
  const int fr = lane & 15, fq = lane >> 4;

  short8v aq[4];
  {
    const int s_row = qb + w * 16 + fr;
    const unsigned short* qp = Qg + (size_t)s_row * HID + h * HD + fq * 8;
    const float* cb = cosT + s_row * 64;
    const float* sb = sinT + s_row * 64;
    const float SC = 0.12751744f;   // log2(e)/sqrt(128)
#pragma unroll
    for (int ks = 0; ks < 4; ++ks) {
      short8v raw = *(const short8v*)(qp + ks * 32);
      short8v ov;
#pragma unroll
      for (int e = 0; e < 4; ++e) {
        float q1 = bf2f((unsigned short)raw[2 * e]);
        float q2 = bf2f((unsigned short)raw[2 * e + 1]);
        int j = ks * 16 + fq * 4 + e;
        float c = cb[j], sn = sb[j];
        ov[2 * e]     = (short)f2bf(SC * (q1 * c - q2 * sn));
        ov[2 * e + 1] = (short)f2bf(SC * (q2 * c + q1 * sn));
      }
      aq[ks] = ov;
    }
  }

  const int kcb = ((tid & 15) * 16) ^ (((tid >> 4) & 7) << 4);
  const unsigned short* pK0 = Kr + ((size_t)hk * S_LEN + (tid >> 4)) * HD + (kcb >> 1);
  const int vcb = ((tid & 7) * 16) ^ (((tid >> 3) & 7) << 4);
  const unsigned short* pV0 = Vt + ((size_t)hk * HD + (tid >> 3)) * S_LEN + (vcb >> 1);

  const int hsel = fq >> 1;
  const int srcA = fr + ((2 * (fq & 1)) << 4);
  const int srcB = fr + ((2 * (fq & 1) + 1) << 4);

  float l_acc = 0.f;
  floatx4 o[8] = {};

#define STAGE(buf, t)                                                           \
  do {                                                                          \
    const unsigned short* pk_ = pK0 + (size_t)(t) * 64 * HD;                    \
    const unsigned short* pv_ = pV0 + (t) * 64;                                 \
    _Pragma("unroll")                                                           \
    for (int j = 0; j < 2; ++j)                                                 \
      gld_lds16(pk_ + (size_t)j * 32 * HD, &Kl[buf][j * 4096 + w * 512]);       \
    _Pragma("unroll")                                                           \
    for (int j = 0; j < 2; ++j)                                                 \
      gld_lds16(pv_ + (size_t)j * 64 * S_LEN, &Vl[buf][j * 4096 + w * 512]);    \
  } while (0)

  STAGE(0, 0);
  asm volatile("s_waitcnt vmcnt(0)" ::: "memory");
  __syncthreads();

  const int nt = 2 * qt + 2;
  int cur = 0;
  for (int t = 0; t < nt; ++t) {
    const int kv0 = t * 64;
    if (t + 1 < nt) STAGE(cur ^ 1, t + 1);

    floatx4 St[4] = {};
    const unsigned short* Kc = &Kl[cur][0];
    const unsigned short* Vc = &Vl[cur][0];
    __builtin_amdgcn_s_setprio(1);
#pragma unroll
    for (int ks = 0; ks < 4; ++ks) {
#pragma unroll
      for (int n = 0; n < 4; ++n) {
        int row = n * 16 + fr;
        int cb = (ks * 64 + fq * 16) ^ ((row & 7) << 4);
        short8v kf = *(const short8v*)&Kc[row * 128 + (cb >> 1)];
        St[n] = __builtin_amdgcn_mfma_f32_16x16x32_bf16(kf, aq[ks], St[n], 0, 0, 0);
      }
    }
    __builtin_amdgcn_s_setprio(0);

    if (t >= 2 * qt) {
#pragma unroll
      for (int n = 0; n < 4; ++n) {
#pragma unroll
        for (int r = 0; r < 4; ++r) {
          int kvg = kv0 + n * 16 + fq * 4 + r;
          if (kvg > qb + w * 16 + fr) St[n][r] = -1e30f;
        }
      }
    }

    unsigned int pk[4][2];
#pragma unroll
    for (int n = 0; n < 4; ++n) {
      float p0 = exp2f(St[n][0]);
      float p1 = exp2f(St[n][1]);
      float p2 = exp2f(St[n][2]);
      float p3 = exp2f(St[n][3]);
      l_acc += (p0 + p1) + (p2 + p3);
      pk[n][0] = cvtpk_bf16(p0, p1);
      pk[n][1] = cvtpk_bf16(p2, p3);
    }

    short8v pa[2];
#pragma unroll
    for (int ks = 0; ks < 2; ++ks) {
      unsigned int v0a = __shfl(pk[2 * ks][0], srcA), v0b = __shfl(pk[2 * ks + 1][0], srcA);
      unsigned int v1a = __shfl(pk[2 * ks][1], srcA), v1b = __shfl(pk[2 * ks + 1][1], srcA);
      unsigned int v2a = __shfl(pk[2 * ks][0], srcB), v2b = __shfl(pk[2 * ks + 1][0], srcB);
      unsigned int v3a = __shfl(pk[2 * ks][1], srcB), v3b = __shfl(pk[2 * ks + 1][1], srcB);
      uint4 u;
      u.x = hsel ? v0b : v0a;
      u.y = hsel ? v1b : v1a;
      u.z = hsel ? v2b : v2a;
      u.w = hsel ? v3b : v3a;
      pa[ks] = *(short8v*)&u;
    }

    __builtin_amdgcn_s_setprio(1);
#pragma unroll
    for (int nf = 0; nf < 8; ++nf) {
#pragma unroll
      for (int ks = 0; ks < 2; ++ks) {
        int row = nf * 16 + fr;
        int cb = (ks * 64 + fq * 16) ^ ((row & 7) << 4);
        short8v bv = *(const short8v*)&Vc[row * 64 + (cb >> 1)];
        o[nf] = __builtin_amdgcn_mfma_f32_16x16x32_bf16(pa[ks], bv, o[nf], 0, 0, 0);
      }
    }
    __builtin_amdgcn_s_setprio(0);

    if (t + 1 < nt) {
      asm volatile("s_waitcnt vmcnt(0)" ::: "memory");
      __syncthreads();
      cur ^= 1;
    }
  }
#undef STAGE

  float L = l_acc;
  L += __shfl_xor(L, 16);
  L += __shfl_xor(L, 32);
  float rinv[4];
#pragma unroll
  for (int r = 0; r < 4; ++r) rinv[r] = 1.0f / __shfl(L, fq * 4 + r);

  unsigned short* aop = Ao + (size_t)(qb + w * 16 + fq * 4) * HID + h * HD + fr;
#pragma unroll
  for (int nf = 0; nf < 8; ++nf)
#pragma unroll
    for (int r = 0; r < 4; ++r)
      aop[(size_t)r * HID + nf * 16] = f2bf(o[nf][r] * rinv[r]);
}

// ---------------- launch ----------------
extern "C" void kernel_launch(void* const* d_in, const int* in_sizes, int n_in,
                              void* d_out, int out_size, void* d_ws, size_t ws_size,
                              hipStream_t stream) {
  (void)in_sizes; (void)n_in; (void)out_size; (void)ws_size;
  const float* X    = (const float*)d_in[0];
  const float* cosT = (const float*)d_in[3];
  const float* sinT = (const float*)d_in[4];
  const float* Wq   = (const float*)d_in[5];
  const float* Wk   = (const float*)d_in[6];
  const float* Wv   = (const float*)d_in[7];
  const float* Wo   = (const float*)d_in[8];

  char* ws = (char*)d_ws;
  size_t off = 0;
  auto alloc = [&](size_t bytes) { char* p = ws + off; off += (bytes + 255) & ~(size_t)255; return p; };
  unsigned short* Xb  = (unsigned short*)alloc((size_t)S_LEN * HID * 2);
  // Wqb/Wkb/Wvb contiguous -> concatenated B matrix [Wq;Wk;Wv] (6144x4096)
  unsigned short* Wqb = (unsigned short*)alloc((size_t)HID * HID * 2);
  unsigned short* Wkb = (unsigned short*)alloc((size_t)1024 * HID * 2);
  unsigned short* Wvb = (unsigned short*)alloc((size_t)1024 * HID * 2);
  unsigned short* Wob = (unsigned short*)alloc((size_t)HID * HID * 2);
  unsigned short* Qg  = (unsigned short*)alloc((size_t)S_LEN * HID * 2);
  unsigned short* Kr  = (unsigned short*)alloc((size_t)S_LEN * 1024 * 2);  // rope'd K [8][2048][128]
  unsigned short* Vt  = (unsigned short*)alloc((size_t)1024 * S_LEN * 2);
  unsigned short* Ao = Xb;       // alias: Xb dead after gemm_qkv

  cvt_all<<<2048, 256, 0, stream>>>(X, Wq, Wk, Wv, Wo, Xb, Wqb, Wkb, Wvb, Wob);
  gemm_qkv<<<dim3(32, 8), 512, 0, stream>>>(Xb, Wqb, cosT, sinT, Qg, Kr, Vt);
  attn_fwd<<<512, 512, 0, stream>>>(Qg, cosT, sinT, Kr, Vt, Ao);
  gemm_o<<<dim3(32, 8), 512, 0, stream>>>(Ao, Wob, (float*)d_out);
}

// Round 17
// 289.671 us; speedup vs baseline: 1.0385x; 1.0147x over previous
//
#include <hip/hip_runtime.h>
#include <hip/hip_bf16.h>

#define S_LEN 2048
#define HID   4096
#define NH    32
#define NKV   8
#define HD    128

typedef __attribute__((ext_vector_type(8))) short short8v;
typedef __attribute__((ext_vector_type(4))) float floatx4;

__device__ __forceinline__ float bf2f(unsigned short u) {
  union { unsigned int u32; float f; } v; v.u32 = ((unsigned int)u) << 16; return v.f;
}
__device__ __forceinline__ unsigned short f2bf(float f) {
  union { float f; unsigned int u; } v; v.f = f;
  unsigned int u = v.u + 0x7fffu + ((v.u >> 16) & 1u);
  return (unsigned short)(u >> 16);
}
__device__ __forceinline__ unsigned int cvtpk_bf16(float lo, float hi) {
  unsigned int r;
  asm("v_cvt_pk_bf16_f32 %0, %1, %2" : "=v"(r) : "v"(lo), "v"(hi));
  return r;
}

__device__ __forceinline__ void gld_lds16(const void* g, void* l) {
  __builtin_amdgcn_global_load_lds((const __attribute__((address_space(1))) void*)g,
                                   (__attribute__((address_space(3))) void*)l, 16, 0, 0);
}

// ---------------- fused f32 -> bf16 convert, 32B-read / 16B-write per iter ----
__global__ __launch_bounds__(256) void cvt_all(const float* __restrict__ X,  const float* __restrict__ Wq,
                                               const float* __restrict__ Wk, const float* __restrict__ Wv,
                                               const float* __restrict__ Wo,
                                               unsigned short* __restrict__ Xb,  unsigned short* __restrict__ Wqb,
                                               unsigned short* __restrict__ Wkb, unsigned short* __restrict__ Wvb,
                                               unsigned short* __restrict__ Wob) {
  const int c0 = 1048576;            // X  (float8 units)
  const int c1 = c0 + 2097152;       // Wq
  const int c2 = c1 + 524288;        // Wk
  const int c3 = c2 + 524288;        // Wv
  const int c4 = c3 + 2097152;       // Wo
  int i = blockIdx.x * blockDim.x + threadIdx.x;
  int stride = gridDim.x * blockDim.x;
  for (; i < c4; i += stride) {
    const float* src; unsigned short* dst; int off;
    if (i < c0)      { src = X;  dst = Xb;  off = i; }
    else if (i < c1) { src = Wq; dst = Wqb; off = i - c0; }
    else if (i < c2) { src = Wk; dst = Wkb; off = i - c1; }
    else if (i < c3) { src = Wv; dst = Wvb; off = i - c2; }
    else             { src = Wo; dst = Wob; off = i - c3; }
    float4 v0 = ((const float4*)src)[2 * off];
    float4 v1 = ((const float4*)src)[2 * off + 1];
    union { ushort4 h[2]; uint4 u; } o;
    o.h[0].x = f2bf(v0.x); o.h[0].y = f2bf(v0.y); o.h[0].z = f2bf(v0.z); o.h[0].w = f2bf(v0.w);
    o.h[1].x = f2bf(v1.x); o.h[1].y = f2bf(v1.y); o.h[1].z = f2bf(v1.z); o.h[1].w = f2bf(v1.w);
    ((uint4*)dst)[off] = o.u;
  }
}

// =====================================================================
// gemm_qkv: 256x192 tile over CONCATENATED B = [Wq;Wk;Wv] (6144x4096).
// Grid (32,8) = 256 equal blocks = perfect CU fill (r14 proven: 110.7 us).
// 512 thr = 8 waves (2M x 4N), wave 128x48 = acc[8][3]. BK=64, 2 kh-phases.
// LDS: A 2 x 32 KB + B 3 x 24 KB = 136 KB. Counted-vmcnt ledger as r14.
// Plain outputs (rope separate — fusions into this epilogue regressed twice).
// =====================================================================
__global__ __launch_bounds__(512, 2) void gemm_qkv(const unsigned short* __restrict__ Xb,
                                                   const unsigned short* __restrict__ Bcat,
                                                   unsigned short* __restrict__ Qg,
                                                   unsigned short* __restrict__ Kg,
                                                   unsigned short* __restrict__ Vt) {
  __shared__ unsigned short lds[2 * 16384 + 3 * 12288];   // 136 KB
  const int K = 4096;
  const int tid = threadIdx.x;
  const int w = tid >> 6, lane = tid & 63;
  const int fr = lane & 15, fq = lane >> 4;
  const int wm = w >> 2, wn = w & 3;
  const int brow = blockIdx.y * 256, bcol = blockIdx.x * 192;

  const int r0s = w * 32 + (lane >> 2);
  const int r1s = r0s + 16;
  const int sl0 = ((lane & 3) ^ ((r0s >> 1) & 3)) << 3;
  const int sl1 = ((lane & 3) ^ ((r1s >> 1) & 3)) << 3;
  const unsigned short* pAs0 = Xb + (size_t)(brow + r0s) * K + sl0;
  const unsigned short* pAs1 = Xb + (size_t)(brow + r1s) * K + sl1;

  const unsigned short* pBs[3];
#pragma unroll
  for (int j = 0; j < 3; ++j) {
    int c = tid + j * 512;
    int khj = (c >= 768) ? 1 : 0;
    int rowj = (c - khj * 768) >> 2;
    int slotj = c & 3;
    pBs[j] = Bcat + (size_t)(bcol + rowj) * K + khj * 32 +
             ((slotj ^ ((rowj >> 1) & 3)) << 3);
  }

  const int sl = (fq ^ ((fr >> 1) & 3)) << 3;
  int aoffb[8], boffb[3];
#pragma unroll
  for (int m = 0; m < 8; ++m) aoffb[m] = (wm * 128 + m * 16 + fr) * 32 + sl;
#pragma unroll
  for (int n = 0; n < 3; ++n) boffb[n] = (wn * 48 + n * 16 + fr) * 32 + sl;

#define STG_A(buf, kh, t)                                                     \
  do {                                                                        \
    const int ko_ = (t) * 64 + (kh) * 32;                                     \
    gld_lds16(pAs0 + ko_, lds + (buf) * 16384 + (kh) * 8192 + w * 1024);      \
    gld_lds16(pAs1 + ko_, lds + (buf) * 16384 + (kh) * 8192 + w * 1024 + 512);\
  } while (0)
#define STG_B(bb, t)                                                          \
  do {                                                                        \
    const int ko_ = (t) * 64;                                                 \
    gld_lds16(pBs[0] + ko_, lds + 32768 + (bb) * 12288 + w * 512);            \
    gld_lds16(pBs[1] + ko_, lds + 32768 + (bb) * 12288 + 4096 + w * 512);     \
    gld_lds16(pBs[2] + ko_, lds + 32768 + (bb) * 12288 + 8192 + w * 512);     \
  } while (0)

  floatx4 acc[8][3] = {};

  STG_A(0, 0, 0); STG_A(0, 1, 0); STG_B(0, 0);
  STG_A(1, 0, 1);                 STG_B(1, 1);
  asm volatile("s_waitcnt vmcnt(5)" ::: "memory");
  __builtin_amdgcn_s_barrier();

  const int NT = K / 64;   // 64
  for (int t = 0; t < NT; ++t) {
    const int c = t & 1;
    const int bb = t % 3;
    const unsigned short* LA = lds + c * 16384;
    const unsigned short* LB = lds + 32768 + bb * 12288;
    short8v a_[8], b_[3];

    // ---- phase 1: kh0 ----
#pragma unroll
    for (int m = 0; m < 8; ++m) a_[m] = *(const short8v*)&LA[aoffb[m]];
#pragma unroll
    for (int n = 0; n < 3; ++n) b_[n] = *(const short8v*)&LB[boffb[n]];
    if (t + 1 < NT) STG_A(c ^ 1, 1, t + 1);
    if (t + 2 < NT) STG_B((bb + 2) % 3, t + 2);
    __builtin_amdgcn_s_setprio(1);
#pragma unroll
    for (int m = 0; m < 8; ++m)
#pragma unroll
      for (int n = 0; n < 3; ++n)
        acc[m][n] = __builtin_amdgcn_mfma_f32_16x16x32_bf16(a_[m], b_[n], acc[m][n], 0, 0, 0);
    __builtin_amdgcn_s_setprio(0);
    if (t + 2 < NT)      asm volatile("s_waitcnt vmcnt(10)" ::: "memory");
    else if (t + 1 < NT) asm volatile("s_waitcnt vmcnt(7)" ::: "memory");
    else                 asm volatile("s_waitcnt vmcnt(0)" ::: "memory");
    __builtin_amdgcn_s_barrier();

    // ---- phase 2: kh1 ----
#pragma unroll
    for (int m = 0; m < 8; ++m) a_[m] = *(const short8v*)&LA[8192 + aoffb[m]];
#pragma unroll
    for (int n = 0; n < 3; ++n) b_[n] = *(const short8v*)&LB[6144 + boffb[n]];
    if (t + 2 < NT) STG_A(c, 0, t + 2);
    __builtin_amdgcn_s_setprio(1);
#pragma unroll
    for (int m = 0; m < 8; ++m)
#pragma unroll
      for (int n = 0; n < 3; ++n)
        acc[m][n] = __builtin_amdgcn_mfma_f32_16x16x32_bf16(a_[m], b_[n], acc[m][n], 0, 0, 0);
    __builtin_amdgcn_s_setprio(0);
    if (t + 2 < NT)      asm volatile("s_waitcnt vmcnt(7)" ::: "memory");
    else if (t + 1 < NT) asm volatile("s_waitcnt vmcnt(2)" ::: "memory");
    else                 asm volatile("s_waitcnt vmcnt(0)" ::: "memory");
    __builtin_amdgcn_s_barrier();
  }
#undef STG_A
#undef STG_B

  // ---- epilogue: per-frag routing (boundaries 4096/5120 are 16-aligned) ----
  const int r0 = brow + wm * 128 + fq * 4;
#pragma unroll
  for (int m = 0; m < 8; ++m)
#pragma unroll
    for (int n = 0; n < 3; ++n) {
      const int bc = bcol + wn * 48 + n * 16;   // frag base col (wave-uniform)
      if (bc < 4096) {
#pragma unroll
        for (int r = 0; r < 4; ++r)
          Qg[(size_t)(r0 + m * 16 + r) * HID + bc + fr] = f2bf(acc[m][n][r]);
      } else if (bc < 5120) {
#pragma unroll
        for (int r = 0; r < 4; ++r)
          Kg[(size_t)(r0 + m * 16 + r) * 1024 + bc - 4096 + fr] = f2bf(acc[m][n][r]);
      } else {
        ushort4 pk;
        pk.x = f2bf(acc[m][n][0]); pk.y = f2bf(acc[m][n][1]);
        pk.z = f2bf(acc[m][n][2]); pk.w = f2bf(acc[m][n][3]);
        *(ushort4*)&Vt[(size_t)(bc - 5120 + fr) * S_LEN + (r0 + m * 16)] = pk;
      }
    }
}

// =====================================================================
// gemm_o: 256x128 / BK=64 / 2-phase / raw-barrier / counted-vmcnt (r10, proven).
// =====================================================================
__global__ __launch_bounds__(512, 2) void gemm_o(const unsigned short* __restrict__ Ao,
                                                 const unsigned short* __restrict__ Wob,
                                                 float* __restrict__ Out) {
  __shared__ unsigned short lds[2 * 24576];   // 96 KB
  const int K = 4096;
  const int tid = threadIdx.x;
  const int w = tid >> 6, lane = tid & 63;
  const int fr = lane & 15, fq = lane >> 4;
  const int wm = w >> 1, wn = w & 1;
  const int brow = blockIdx.y * 256, bcol = blockIdx.x * 128;

  const int rA = tid >> 2;
  const int sA = ((tid & 3) ^ ((rA >> 1) & 3)) << 3;
  const unsigned short* pA0 = Ao  + (size_t)(brow + rA) * K + sA;
  const unsigned short* pA1 = Ao  + (size_t)(brow + 128 + rA) * K + sA;
  const unsigned short* pB0 = Wob + (size_t)(bcol + rA) * K + sA;

  const int sl = (fq ^ ((fr >> 1) & 3)) << 3;
  int aoff[4], boff[4];
#pragma unroll
  for (int m = 0; m < 4; ++m) aoff[m] = (wm * 64 + m * 16 + fr) * 32 + sl;
#pragma unroll
  for (int n = 0; n < 4; ++n) boff[n] = 16384 + (wn * 64 + n * 16 + fr) * 32 + sl;

  floatx4 acc[4][4] = {};

#define STG_KH(buf, kh, t)                                                       \
  do {                                                                           \
    const int ko_ = (t) * 64 + (kh) * 32;                                        \
    gld_lds16(pA0 + ko_, lds + (buf) * 24576 + (kh) * 8192 + w * 512);           \
    gld_lds16(pA1 + ko_, lds + (buf) * 24576 + (kh) * 8192 + 4096 + w * 512);    \
    gld_lds16(pB0 + ko_, lds + (buf) * 24576 + 16384 + (kh) * 4096 + w * 512);   \
  } while (0)

  STG_KH(0, 0, 0);
  STG_KH(0, 1, 0);
  STG_KH(1, 0, 1);
  asm volatile("s_waitcnt vmcnt(6)" ::: "memory");
  __builtin_amdgcn_s_barrier();

  const int NT = K / 64;   // 64
  for (int t = 0; t < NT; ++t) {
    const int c = t & 1;
    const unsigned short* Lc = lds + c * 24576;
    short8v a_[4], b_[4];

#pragma unroll
    for (int m = 0; m < 4; ++m) a_[m] = *(const short8v*)&Lc[aoff[m]];
#pragma unroll
    for (int n = 0; n < 4; ++n) b_[n] = *(const short8v*)&Lc[boff[n]];
    if (t + 1 < NT) STG_KH(c ^ 1, 1, t + 1);
    __builtin_amdgcn_s_setprio(1);
#pragma unroll
    for (int m = 0; m < 4; ++m)
#pragma unroll
      for (int n = 0; n < 4; ++n)
        acc[m][n] = __builtin_amdgcn_mfma_f32_16x16x32_bf16(a_[m], b_[n], acc[m][n], 0, 0, 0);
    __builtin_amdgcn_s_setprio(0);
    if (t + 1 < NT) asm volatile("s_waitcnt vmcnt(6)" ::: "memory");
    else            asm volatile("s_waitcnt vmcnt(0)" ::: "memory");
    __builtin_amdgcn_s_barrier();

#pragma unroll
    for (int m = 0; m < 4; ++m) a_[m] = *(const short8v*)&Lc[8192 + aoff[m]];
#pragma unroll
    for (int n = 0; n < 4; ++n) b_[n] = *(const short8v*)&Lc[4096 + boff[n]];
    if (t + 2 < NT) STG_KH(c, 0, t + 2);
    __builtin_amdgcn_s_setprio(1);
#pragma unroll
    for (int m = 0; m < 4; ++m)
#pragma unroll
      for (int n = 0; n < 4; ++n)
        acc[m][n] = __builtin_amdgcn_mfma_f32_16x16x32_bf16(a_[m], b_[n], acc[m][n], 0, 0, 0);
    __builtin_amdgcn_s_setprio(0);
    if (t + 2 < NT)      asm volatile("s_waitcnt vmcnt(6)" ::: "memory");
    else if (t + 1 < NT) asm volatile("s_waitcnt vmcnt(3)" ::: "memory");
    else                 asm volatile("s_waitcnt vmcnt(0)" ::: "memory");
    __builtin_amdgcn_s_barrier();
  }
#undef STG_KH

  const int r0 = brow + wm * 64 + fq * 4;
  const int c0 = bcol + wn * 64 + fr;
#pragma unroll
  for (int m = 0; m < 4; ++m)
#pragma unroll
    for (int n = 0; n < 4; ++n)
#pragma unroll
      for (int r = 0; r < 4; ++r)
        Out[(size_t)(r0 + m * 16 + r) * HID + c0 + n * 16] = acc[m][n][r];
}

// ---------------- K RoPE: INTERLEAVED layout (pair results at 2j, 2j+1) ------
__global__ __launch_bounds__(256) void rope_k(const unsigned short* __restrict__ In,
                                              const float* __restrict__ cosT,
                                              const float* __restrict__ sinT,
                                              unsigned short* __restrict__ Out) {
  int idx = blockIdx.x * 256 + threadIdx.x;
  int j = idx & 63;
  int s = (idx >> 6) & (S_LEN - 1);
  int h = idx >> 17;
  unsigned int pr = *(const unsigned int*)(In + (size_t)s * (NKV * HD) + h * HD + 2 * j);
  float k1 = bf2f((unsigned short)(pr & 0xffffu));
  float k2 = bf2f((unsigned short)(pr >> 16));
  float c = cosT[s * 64 + j], sn = sinT[s * 64 + j];
  unsigned int pk = (unsigned int)f2bf(k1 * c - k2 * sn) |
                    ((unsigned int)f2bf(k2 * c + k1 * sn) << 16);
  *(unsigned int*)(Out + ((size_t)h * S_LEN + s) * HD + 2 * j) = pk;
}

// ---------------- Flash attention: 8-wave blocks, shared K/V tile (r12, proven)
__global__ __launch_bounds__(512, 4) void attn_fwd(const unsigned short* __restrict__ Qg,
                                                   const float* __restrict__ cosT,
                                                   const float* __restrict__ sinT,
                                                   const unsigned short* __restrict__ Kr,
                                                   const unsigned short* __restrict__ Vt,
                                                   unsigned short* __restrict__ Ao) {
  __shared__ unsigned short Kl[2][64 * 128];   // [kv][128], swizzled (cb ^ (row&7)<<4)
  __shared__ unsigned short Vl[2][128 * 64];   // [d][kv], swizzled
  const int id = blockIdx.x;
  const int xcd = id & 7, rr = id >> 3;
  const int qt = 15 - (rr >> 2);               // heavy first
  const int h  = xcd * 4 + (rr & 3);           // XCD c <-> kv-head c
  const int hk = h >> 2;
  const int qb = qt * 128;
  const int tid = threadIdx.x, w = tid >> 6, lane = tid & 63;
  const int fr = lane & 15, fq = lane >> 4;

  short8v aq[4];
  {
    const int s_row = qb + w * 16 + fr;
    const unsigned short* qp = Qg + (size_t)s_row * HID + h * HD + fq * 8;
    const float* cb = cosT + s_row * 64;
    const float* sb = sinT + s_row * 64;
    const float SC = 0.12751744f;   // log2(e)/sqrt(128)
#pragma unroll
    for (int ks = 0; ks < 4; ++ks) {
      short8v raw = *(const short8v*)(qp + ks * 32);
      short8v ov;
#pragma unroll
      for (int e = 0; e < 4; ++e) {
        float q1 = bf2f((unsigned short)raw[2 * e]);
        float q2 = bf2f((unsigned short)raw[2 * e + 1]);
        int j = ks * 16 + fq * 4 + e;
        float c = cb[j], sn = sb[j];
        ov[2 * e]     = (short)f2bf(SC * (q1 * c - q2 * sn));
        ov[2 * e + 1] = (short)f2bf(SC * (q2 * c + q1 * sn));
      }
      aq[ks] = ov;
    }
  }

  const int kcb = ((tid & 15) * 16) ^ (((tid >> 4) & 7) << 4);
  const unsigned short* pK0 = Kr + ((size_t)hk * S_LEN + (tid >> 4)) * HD + (kcb >> 1);
  const int vcb = ((tid & 7) * 16) ^ (((tid >> 3) & 7) << 4);
  const unsigned short* pV0 = Vt + ((size_t)hk * HD + (tid >> 3)) * S_LEN + (vcb >> 1);

  const int hsel = fq >> 1;
  const int srcA = fr + ((2 * (fq & 1)) << 4);
  const int srcB = fr + ((2 * (fq & 1) + 1) << 4);

  float l_acc = 0.f;
  floatx4 o[8] = {};

#define STAGE(buf, t)                                                           \
  do {                                                                          \
    const unsigned short* pk_ = pK0 + (size_t)(t) * 64 * HD;                    \
    const unsigned short* pv_ = pV0 + (t) * 64;                                 \
    _Pragma("unroll")                                                           \
    for (int j = 0; j < 2; ++j)                                                 \
      gld_lds16(pk_ + (size_t)j * 32 * HD, &Kl[buf][j * 4096 + w * 512]);       \
    _Pragma("unroll")                                                           \
    for (int j = 0; j < 2; ++j)                                                 \
      gld_lds16(pv_ + (size_t)j * 64 * S_LEN, &Vl[buf][j * 4096 + w * 512]);    \
  } while (0)

  STAGE(0, 0);
  asm volatile("s_waitcnt vmcnt(0)" ::: "memory");
  __syncthreads();

  const int nt = 2 * qt + 2;
  int cur = 0;
  for (int t = 0; t < nt; ++t) {
    const int kv0 = t * 64;
    if (t + 1 < nt) STAGE(cur ^ 1, t + 1);

    floatx4 St[4] = {};
    const unsigned short* Kc = &Kl[cur][0];
    const unsigned short* Vc = &Vl[cur][0];
    __builtin_amdgcn_s_setprio(1);
#pragma unroll
    for (int ks = 0; ks < 4; ++ks) {
#pragma unroll
      for (int n = 0; n < 4; ++n) {
        int row = n * 16 + fr;
        int cb = (ks * 64 + fq * 16) ^ ((row & 7) << 4);
        short8v kf = *(const short8v*)&Kc[row * 128 + (cb >> 1)];
        St[n] = __builtin_amdgcn_mfma_f32_16x16x32_bf16(kf, aq[ks], St[n], 0, 0, 0);
      }
    }
    __builtin_amdgcn_s_setprio(0);

    if (t >= 2 * qt) {
#pragma unroll
      for (int n = 0; n < 4; ++n) {
#pragma unroll
        for (int r = 0; r < 4; ++r) {
          int kvg = kv0 + n * 16 + fq * 4 + r;
          if (kvg > qb + w * 16 + fr) St[n][r] = -1e30f;
        }
      }
    }

    unsigned int pk[4][2];
#pragma unroll
    for (int n = 0; n < 4; ++n) {
      float p0 = exp2f(St[n][0]);
      float p1 = exp2f(St[n][1]);
      float p2 = exp2f(St[n][2]);
      float p3 = exp2f(St[n][3]);
      l_acc += (p0 + p1) + (p2 + p3);
      pk[n][0] = cvtpk_bf16(p0, p1);
      pk[n][1] = cvtpk_bf16(p2, p3);
    }

    short8v pa[2];
#pragma unroll
    for (int ks = 0; ks < 2; ++ks) {
      unsigned int v0a = __shfl(pk[2 * ks][0], srcA), v0b = __shfl(pk[2 * ks + 1][0], srcA);
      unsigned int v1a = __shfl(pk[2 * ks][1], srcA), v1b = __shfl(pk[2 * ks + 1][1], srcA);
      unsigned int v2a = __shfl(pk[2 * ks][0], srcB), v2b = __shfl(pk[2 * ks + 1][0], srcB);
      unsigned int v3a = __shfl(pk[2 * ks][1], srcB), v3b = __shfl(pk[2 * ks + 1][1], srcB);
      uint4 u;
      u.x = hsel ? v0b : v0a;
      u.y = hsel ? v1b : v1a;
      u.z = hsel ? v2b : v2a;
      u.w = hsel ? v3b : v3a;
      pa[ks] = *(short8v*)&u;
    }

    __builtin_amdgcn_s_setprio(1);
#pragma unroll
    for (int nf = 0; nf < 8; ++nf) {
#pragma unroll
      for (int ks = 0; ks < 2; ++ks) {
        int row = nf * 16 + fr;
        int cb = (ks * 64 + fq * 16) ^ ((row & 7) << 4);
        short8v bv = *(const short8v*)&Vc[row * 64 + (cb >> 1)];
        o[nf] = __builtin_amdgcn_mfma_f32_16x16x32_bf16(pa[ks], bv, o[nf], 0, 0, 0);
      }
    }
    __builtin_amdgcn_s_setprio(0);

    if (t + 1 < nt) {
      asm volatile("s_waitcnt vmcnt(0)" ::: "memory");
      __syncthreads();
      cur ^= 1;
    }
  }
#undef STAGE

  float L = l_acc;
  L += __shfl_xor(L, 16);
  L += __shfl_xor(L, 32);
  float rinv[4];
#pragma unroll
  for (int r = 0; r < 4; ++r) rinv[r] = 1.0f / __shfl(L, fq * 4 + r);

  unsigned short* aop = Ao + (size_t)(qb + w * 16 + fq * 4) * HID + h * HD + fr;
#pragma unroll
  for (int nf = 0; nf < 8; ++nf)
#pragma unroll
    for (int r = 0; r < 4; ++r)
      aop[(size_t)r * HID + nf * 16] = f2bf(o[nf][r] * rinv[r]);
}

// ---------------- launch ----------------
extern "C" void kernel_launch(void* const* d_in, const int* in_sizes, int n_in,
                              void* d_out, int out_size, void* d_ws, size_t ws_size,
                              hipStream_t stream) {
  (void)in_sizes; (void)n_in; (void)out_size; (void)ws_size;
  const float* X    = (const float*)d_in[0];
  const float* cosT = (const float*)d_in[3];
  const float* sinT = (const float*)d_in[4];
  const float* Wq   = (const float*)d_in[5];
  const float* Wk   = (const float*)d_in[6];
  const float* Wv   = (const float*)d_in[7];
  const float* Wo   = (const float*)d_in[8];

  char* ws = (char*)d_ws;
  size_t off = 0;
  auto alloc = [&](size_t bytes) { char* p = ws + off; off += (bytes + 255) & ~(size_t)255; return p; };
  unsigned short* Xb  = (unsigned short*)alloc((size_t)S_LEN * HID * 2);
  // Wqb/Wkb/Wvb contiguous -> concatenated B matrix [Wq;Wk;Wv] (6144x4096)
  unsigned short* Wqb = (unsigned short*)alloc((size_t)HID * HID * 2);
  unsigned short* Wkb = (unsigned short*)alloc((size_t)1024 * HID * 2);
  unsigned short* Wvb = (unsigned short*)alloc((size_t)1024 * HID * 2);
  unsigned short* Wob = (unsigned short*)alloc((size_t)HID * HID * 2);
  unsigned short* Qg  = (unsigned short*)alloc((size_t)S_LEN * HID * 2);
  unsigned short* Kg  = (unsigned short*)alloc((size_t)S_LEN * 1024 * 2);
  unsigned short* Vt  = (unsigned short*)alloc((size_t)1024 * S_LEN * 2);
  unsigned short* Kr = Wqb;      // alias: Wqb dead after gemm_qkv
  unsigned short* Ao = Xb;       // alias: Xb dead after gemm_qkv

  cvt_all<<<2048, 256, 0, stream>>>(X, Wq, Wk, Wv, Wo, Xb, Wqb, Wkb, Wvb, Wob);
  gemm_qkv<<<dim3(32, 8), 512, 0, stream>>>(Xb, Wqb, Qg, Kg, Vt);
  rope_k<<<(NKV * S_LEN * 64) / 256, 256, 0, stream>>>(Kg, cosT, sinT, Kr);
  attn_fwd<<<512, 512, 0, stream>>>(Qg, cosT, sinT, Kr, Vt, Ao);
  gemm_o<<<dim3(32, 8), 512, 0, stream>>>(Ao, Wob, (float*)d_out);
}

// Round 18
// 285.324 us; speedup vs baseline: 1.0543x; 1.0152x over previous
//
#include <hip/hip_runtime.h>
#include <hip/hip_bf16.h>

#define S_LEN 2048
#define HID   4096
#define NH    32
#define NKV   8
#define HD    128

typedef __attribute__((ext_vector_type(8))) short short8v;
typedef __attribute__((ext_vector_type(4))) float floatx4;

__device__ __forceinline__ float bf2f(unsigned short u) {
  union { unsigned int u32; float f; } v; v.u32 = ((unsigned int)u) << 16; return v.f;
}
__device__ __forceinline__ unsigned short f2bf(float f) {
  union { float f; unsigned int u; } v; v.f = f;
  unsigned int u = v.u + 0x7fffu + ((v.u >> 16) & 1u);
  return (unsigned short)(u >> 16);
}
__device__ __forceinline__ unsigned int cvtpk_bf16(float lo, float hi) {
  unsigned int r;
  asm("v_cvt_pk_bf16_f32 %0, %1, %2" : "=v"(r) : "v"(lo), "v"(hi));
  return r;
}

__device__ __forceinline__ void gld_lds16(const void* g, void* l) {
  __builtin_amdgcn_global_load_lds((const __attribute__((address_space(1))) void*)g,
                                   (__attribute__((address_space(3))) void*)l, 16, 0, 0);
}

// ---------------- fused f32 -> bf16 convert, 32B-read / 16B-write per iter ----
__global__ __launch_bounds__(256) void cvt_all(const float* __restrict__ X,  const float* __restrict__ Wq,
                                               const float* __restrict__ Wk, const float* __restrict__ Wv,
                                               const float* __restrict__ Wo,
                                               unsigned short* __restrict__ Xb,  unsigned short* __restrict__ Wqb,
                                               unsigned short* __restrict__ Wkb, unsigned short* __restrict__ Wvb,
                                               unsigned short* __restrict__ Wob) {
  const int c0 = 1048576;            // X  (float8 units)
  const int c1 = c0 + 2097152;       // Wq
  const int c2 = c1 + 524288;        // Wk
  const int c3 = c2 + 524288;        // Wv
  const int c4 = c3 + 2097152;       // Wo
  int i = blockIdx.x * blockDim.x + threadIdx.x;
  int stride = gridDim.x * blockDim.x;
  for (; i < c4; i += stride) {
    const float* src; unsigned short* dst; int off;
    if (i < c0)      { src = X;  dst = Xb;  off = i; }
    else if (i < c1) { src = Wq; dst = Wqb; off = i - c0; }
    else if (i < c2) { src = Wk; dst = Wkb; off = i - c1; }
    else if (i < c3) { src = Wv; dst = Wvb; off = i - c2; }
    else             { src = Wo; dst = Wob; off = i - c3; }
    float4 v0 = ((const float4*)src)[2 * off];
    float4 v1 = ((const float4*)src)[2 * off + 1];
    union { ushort4 h[2]; uint4 u; } o;
    o.h[0].x = f2bf(v0.x); o.h[0].y = f2bf(v0.y); o.h[0].z = f2bf(v0.z); o.h[0].w = f2bf(v0.w);
    o.h[1].x = f2bf(v1.x); o.h[1].y = f2bf(v1.y); o.h[1].z = f2bf(v1.z); o.h[1].w = f2bf(v1.w);
    ((uint4*)dst)[off] = o.u;
  }
}

// =====================================================================
// gemm_qkv: 256x192 tile over CONCATENATED B = [Wq;Wk;Wv] (6144x4096).
// Grid (32,8) = 256 equal blocks = perfect CU fill (r14 proven: 110.7 us).
// UNCHANGED from the proven r14/r17 configuration.
// =====================================================================
__global__ __launch_bounds__(512, 2) void gemm_qkv(const unsigned short* __restrict__ Xb,
                                                   const unsigned short* __restrict__ Bcat,
                                                   unsigned short* __restrict__ Qg,
                                                   unsigned short* __restrict__ Kg,
                                                   unsigned short* __restrict__ Vt) {
  __shared__ unsigned short lds[2 * 16384 + 3 * 12288];   // 136 KB
  const int K = 4096;
  const int tid = threadIdx.x;
  const int w = tid >> 6, lane = tid & 63;
  const int fr = lane & 15, fq = lane >> 4;
  const int wm = w >> 2, wn = w & 3;
  const int brow = blockIdx.y * 256, bcol = blockIdx.x * 192;

  const int r0s = w * 32 + (lane >> 2);
  const int r1s = r0s + 16;
  const int sl0 = ((lane & 3) ^ ((r0s >> 1) & 3)) << 3;
  const int sl1 = ((lane & 3) ^ ((r1s >> 1) & 3)) << 3;
  const unsigned short* pAs0 = Xb + (size_t)(brow + r0s) * K + sl0;
  const unsigned short* pAs1 = Xb + (size_t)(brow + r1s) * K + sl1;

  const unsigned short* pBs[3];
#pragma unroll
  for (int j = 0; j < 3; ++j) {
    int c = tid + j * 512;
    int khj = (c >= 768) ? 1 : 0;
    int rowj = (c - khj * 768) >> 2;
    int slotj = c & 3;
    pBs[j] = Bcat + (size_t)(bcol + rowj) * K + khj * 32 +
             ((slotj ^ ((rowj >> 1) & 3)) << 3);
  }

  const int sl = (fq ^ ((fr >> 1) & 3)) << 3;
  int aoffb[8], boffb[3];
#pragma unroll
  for (int m = 0; m < 8; ++m) aoffb[m] = (wm * 128 + m * 16 + fr) * 32 + sl;
#pragma unroll
  for (int n = 0; n < 3; ++n) boffb[n] = (wn * 48 + n * 16 + fr) * 32 + sl;

#define STG_A(buf, kh, t)                                                     \
  do {                                                                        \
    const int ko_ = (t) * 64 + (kh) * 32;                                     \
    gld_lds16(pAs0 + ko_, lds + (buf) * 16384 + (kh) * 8192 + w * 1024);      \
    gld_lds16(pAs1 + ko_, lds + (buf) * 16384 + (kh) * 8192 + w * 1024 + 512);\
  } while (0)
#define STG_B(bb, t)                                                          \
  do {                                                                        \
    const int ko_ = (t) * 64;                                                 \
    gld_lds16(pBs[0] + ko_, lds + 32768 + (bb) * 12288 + w * 512);            \
    gld_lds16(pBs[1] + ko_, lds + 32768 + (bb) * 12288 + 4096 + w * 512);     \
    gld_lds16(pBs[2] + ko_, lds + 32768 + (bb) * 12288 + 8192 + w * 512);     \
  } while (0)

  floatx4 acc[8][3] = {};

  STG_A(0, 0, 0); STG_A(0, 1, 0); STG_B(0, 0);
  STG_A(1, 0, 1);                 STG_B(1, 1);
  asm volatile("s_waitcnt vmcnt(5)" ::: "memory");
  __builtin_amdgcn_s_barrier();

  const int NT = K / 64;   // 64
  for (int t = 0; t < NT; ++t) {
    const int c = t & 1;
    const int bb = t % 3;
    const unsigned short* LA = lds + c * 16384;
    const unsigned short* LB = lds + 32768 + bb * 12288;
    short8v a_[8], b_[3];

    // ---- phase 1: kh0 ----
#pragma unroll
    for (int m = 0; m < 8; ++m) a_[m] = *(const short8v*)&LA[aoffb[m]];
#pragma unroll
    for (int n = 0; n < 3; ++n) b_[n] = *(const short8v*)&LB[boffb[n]];
    if (t + 1 < NT) STG_A(c ^ 1, 1, t + 1);
    if (t + 2 < NT) STG_B((bb + 2) % 3, t + 2);
    __builtin_amdgcn_s_setprio(1);
#pragma unroll
    for (int m = 0; m < 8; ++m)
#pragma unroll
      for (int n = 0; n < 3; ++n)
        acc[m][n] = __builtin_amdgcn_mfma_f32_16x16x32_bf16(a_[m], b_[n], acc[m][n], 0, 0, 0);
    __builtin_amdgcn_s_setprio(0);
    if (t + 2 < NT)      asm volatile("s_waitcnt vmcnt(10)" ::: "memory");
    else if (t + 1 < NT) asm volatile("s_waitcnt vmcnt(7)" ::: "memory");
    else                 asm volatile("s_waitcnt vmcnt(0)" ::: "memory");
    __builtin_amdgcn_s_barrier();

    // ---- phase 2: kh1 ----
#pragma unroll
    for (int m = 0; m < 8; ++m) a_[m] = *(const short8v*)&LA[8192 + aoffb[m]];
#pragma unroll
    for (int n = 0; n < 3; ++n) b_[n] = *(const short8v*)&LB[6144 + boffb[n]];
    if (t + 2 < NT) STG_A(c, 0, t + 2);
    __builtin_amdgcn_s_setprio(1);
#pragma unroll
    for (int m = 0; m < 8; ++m)
#pragma unroll
      for (int n = 0; n < 3; ++n)
        acc[m][n] = __builtin_amdgcn_mfma_f32_16x16x32_bf16(a_[m], b_[n], acc[m][n], 0, 0, 0);
    __builtin_amdgcn_s_setprio(0);
    if (t + 2 < NT)      asm volatile("s_waitcnt vmcnt(7)" ::: "memory");
    else if (t + 1 < NT) asm volatile("s_waitcnt vmcnt(2)" ::: "memory");
    else                 asm volatile("s_waitcnt vmcnt(0)" ::: "memory");
    __builtin_amdgcn_s_barrier();
  }
#undef STG_A
#undef STG_B

  // ---- epilogue: per-frag routing (boundaries 4096/5120 are 16-aligned) ----
  const int r0 = brow + wm * 128 + fq * 4;
#pragma unroll
  for (int m = 0; m < 8; ++m)
#pragma unroll
    for (int n = 0; n < 3; ++n) {
      const int bc = bcol + wn * 48 + n * 16;   // frag base col (wave-uniform)
      if (bc < 4096) {
#pragma unroll
        for (int r = 0; r < 4; ++r)
          Qg[(size_t)(r0 + m * 16 + r) * HID + bc + fr] = f2bf(acc[m][n][r]);
      } else if (bc < 5120) {
#pragma unroll
        for (int r = 0; r < 4; ++r)
          Kg[(size_t)(r0 + m * 16 + r) * 1024 + bc - 4096 + fr] = f2bf(acc[m][n][r]);
      } else {
        ushort4 pk;
        pk.x = f2bf(acc[m][n][0]); pk.y = f2bf(acc[m][n][1]);
        pk.z = f2bf(acc[m][n][2]); pk.w = f2bf(acc[m][n][3]);
        *(ushort4*)&Vt[(size_t)(bc - 5120 + fr) * S_LEN + (r0 + m * 16)] = pk;
      }
    }
}

// =====================================================================
// gemm_o: 256x128 / BK=64 / TRIPLE-BUFFERED single-phase-per-tile.
// LDS: A 3 x 32 KB + B 3 x 16 KB = 144 KB (<=160). Grid (32,8) = 256 blocks.
// Per tile t (buf a3 = t%3): read ALL 16 frags (kh0+kh1), stage full T(t+2)
// into buf (t+2)%3 (disjoint from t%3 and (t+1)%3 -> NO mid-tile race, NO
// mid-tile barrier), one 32-MFMA setprio cluster, vmcnt(6), ONE barrier.
// Ledger (6 loads/tile): prologue T0,T1 (12) -> vmcnt(6) = T0 landed.
// Steady: out 6 -> +6 -> vmcnt(6) retires exactly T(t+1). Epilogue:
// t=NT-2 -> vmcnt(0) (drain T(NT-1)); t=NT-1 -> none. Barriers 128 -> 64.
// Write-safety: buf (t+2)%3's previous reader is tile t-1, whose reads
// completed before its end-of-tile barrier, which precedes this stage.
// =====================================================================
__global__ __launch_bounds__(512, 2) void gemm_o(const unsigned short* __restrict__ Ao,
                                                 const unsigned short* __restrict__ Wob,
                                                 float* __restrict__ Out) {
  __shared__ unsigned short lds[73728];   // 144 KB: A 3*16384, B base 49152 + 3*8192
  const int K = 4096;
  const int tid = threadIdx.x;
  const int w = tid >> 6, lane = tid & 63;
  const int fr = lane & 15, fq = lane >> 4;
  const int wm = w >> 1, wn = w & 1;
  const int brow = blockIdx.y * 256, bcol = blockIdx.x * 128;

  const int rA = tid >> 2;
  const int sA = ((tid & 3) ^ ((rA >> 1) & 3)) << 3;
  const unsigned short* pA0 = Ao  + (size_t)(brow + rA) * K + sA;
  const unsigned short* pA1 = Ao  + (size_t)(brow + 128 + rA) * K + sA;
  const unsigned short* pB0 = Wob + (size_t)(bcol + rA) * K + sA;

  const int sl = (fq ^ ((fr >> 1) & 3)) << 3;
  int aoff[4], boff[4];
#pragma unroll
  for (int m = 0; m < 4; ++m) aoff[m] = (wm * 64 + m * 16 + fr) * 32 + sl;
#pragma unroll
  for (int n = 0; n < 4; ++n) boff[n] = (wn * 64 + n * 16 + fr) * 32 + sl;

  floatx4 acc[4][4] = {};

  // stage one kh-half of tile t into buffer `buf` (3 loads)
#define STG_KH(buf, kh, t)                                                       \
  do {                                                                           \
    const int ko_ = (t) * 64 + (kh) * 32;                                        \
    gld_lds16(pA0 + ko_, lds + (buf) * 16384 + (kh) * 8192 + w * 512);           \
    gld_lds16(pA1 + ko_, lds + (buf) * 16384 + (kh) * 8192 + 4096 + w * 512);    \
    gld_lds16(pB0 + ko_, lds + 49152 + (buf) * 8192 + (kh) * 4096 + w * 512);    \
  } while (0)

  // prologue: T0 -> buf0, T1 -> buf1 (12 loads); wait T0 (6 remain)
  STG_KH(0, 0, 0); STG_KH(0, 1, 0);
  STG_KH(1, 0, 1); STG_KH(1, 1, 1);
  asm volatile("s_waitcnt vmcnt(6)" ::: "memory");
  __builtin_amdgcn_s_barrier();

  const int NT = K / 64;   // 64
  int a3 = 0;              // t % 3
  for (int t = 0; t < NT; ++t) {
    const unsigned short* LA = lds + a3 * 16384;
    const unsigned short* LB = lds + 49152 + a3 * 8192;
    short8v a0_[4], b0_[4], a1_[4], b1_[4];

    // read ALL frags for this tile (kh0 + kh1)
#pragma unroll
    for (int m = 0; m < 4; ++m) a0_[m] = *(const short8v*)&LA[aoff[m]];
#pragma unroll
    for (int n = 0; n < 4; ++n) b0_[n] = *(const short8v*)&LB[boff[n]];
#pragma unroll
    for (int m = 0; m < 4; ++m) a1_[m] = *(const short8v*)&LA[8192 + aoff[m]];
#pragma unroll
    for (int n = 0; n < 4; ++n) b1_[n] = *(const short8v*)&LB[4096 + boff[n]];

    // stage T(t+2) into buf (t+2)%3 (disjoint from current & next)
    if (t + 2 < NT) {
      const int nb = (a3 + 2 >= 3) ? a3 - 1 : a3 + 2;   // (t+2)%3
      STG_KH(nb, 0, t + 2);
      STG_KH(nb, 1, t + 2);
    }

    __builtin_amdgcn_s_setprio(1);
#pragma unroll
    for (int m = 0; m < 4; ++m)
#pragma unroll
      for (int n = 0; n < 4; ++n)
        acc[m][n] = __builtin_amdgcn_mfma_f32_16x16x32_bf16(a0_[m], b0_[n], acc[m][n], 0, 0, 0);
#pragma unroll
    for (int m = 0; m < 4; ++m)
#pragma unroll
      for (int n = 0; n < 4; ++n)
        acc[m][n] = __builtin_amdgcn_mfma_f32_16x16x32_bf16(a1_[m], b1_[n], acc[m][n], 0, 0, 0);
    __builtin_amdgcn_s_setprio(0);

    if (t + 2 < NT)      asm volatile("s_waitcnt vmcnt(6)" ::: "memory");  // T(t+1) landed
    else if (t + 1 < NT) asm volatile("s_waitcnt vmcnt(0)" ::: "memory");  // drain last
    if (t + 1 < NT) __builtin_amdgcn_s_barrier();
    a3 = (a3 == 2) ? 0 : a3 + 1;
  }
#undef STG_KH

  const int r0 = brow + wm * 64 + fq * 4;
  const int c0 = bcol + wn * 64 + fr;
#pragma unroll
  for (int m = 0; m < 4; ++m)
#pragma unroll
    for (int n = 0; n < 4; ++n)
#pragma unroll
      for (int r = 0; r < 4; ++r)
        Out[(size_t)(r0 + m * 16 + r) * HID + c0 + n * 16] = acc[m][n][r];
}

// ---------------- K RoPE: INTERLEAVED layout (pair results at 2j, 2j+1) ------
__global__ __launch_bounds__(256) void rope_k(const unsigned short* __restrict__ In,
                                              const float* __restrict__ cosT,
                                              const float* __restrict__ sinT,
                                              unsigned short* __restrict__ Out) {
  int idx = blockIdx.x * 256 + threadIdx.x;
  int j = idx & 63;
  int s = (idx >> 6) & (S_LEN - 1);
  int h = idx >> 17;
  unsigned int pr = *(const unsigned int*)(In + (size_t)s * (NKV * HD) + h * HD + 2 * j);
  float k1 = bf2f((unsigned short)(pr & 0xffffu));
  float k2 = bf2f((unsigned short)(pr >> 16));
  float c = cosT[s * 64 + j], sn = sinT[s * 64 + j];
  unsigned int pk = (unsigned int)f2bf(k1 * c - k2 * sn) |
                    ((unsigned int)f2bf(k2 * c + k1 * sn) << 16);
  *(unsigned int*)(Out + ((size_t)h * S_LEN + s) * HD + 2 * j) = pk;
}

// ---------------- Flash attention: 8-wave blocks, shared K/V tile (r12, proven)
__global__ __launch_bounds__(512, 4) void attn_fwd(const unsigned short* __restrict__ Qg,
                                                   const float* __restrict__ cosT,
                                                   const float* __restrict__ sinT,
                                                   const unsigned short* __restrict__ Kr,
                                                   const unsigned short* __restrict__ Vt,
                                                   unsigned short* __restrict__ Ao) {
  __shared__ unsigned short Kl[2][64 * 128];   // [kv][128], swizzled (cb ^ (row&7)<<4)
  __shared__ unsigned short Vl[2][128 * 64];   // [d][kv], swizzled
  const int id = blockIdx.x;
  const int xcd = id & 7, rr = id >> 3;
  const int qt = 15 - (rr >> 2);               // heavy first
  const int h  = xcd * 4 + (rr & 3);           // XCD c <-> kv-head c
  const int hk = h >> 2;
  const int qb = qt * 128;
  const int tid = threadIdx.x, w = tid >> 6, lane = tid & 63;
  const int fr = lane & 15, fq = lane >> 4;

  short8v aq[4];
  {
    const int s_row = qb + w * 16 + fr;
    const unsigned short* qp = Qg + (size_t)s_row * HID + h * HD + fq * 8;
    const float* cb = cosT + s_row * 64;
    const float* sb = sinT + s_row * 64;
    const float SC = 0.12751744f;   // log2(e)/sqrt(128)
#pragma unroll
    for (int ks = 0; ks < 4; ++ks) {
      short8v raw = *(const short8v*)(qp + ks * 32);
      short8v ov;
#pragma unroll
      for (int e = 0; e < 4; ++e) {
        float q1 = bf2f((unsigned short)raw[2 * e]);
        float q2 = bf2f((unsigned short)raw[2 * e + 1]);
        int j = ks * 16 + fq * 4 + e;
        float c = cb[j], sn = sb[j];
        ov[2 * e]     = (short)f2bf(SC * (q1 * c - q2 * sn));
        ov[2 * e + 1] = (short)f2bf(SC * (q2 * c + q1 * sn));
      }
      aq[ks] = ov;
    }
  }

  const int kcb = ((tid & 15) * 16) ^ (((tid >> 4) & 7) << 4);
  const unsigned short* pK0 = Kr + ((size_t)hk * S_LEN + (tid >> 4)) * HD + (kcb >> 1);
  const int vcb = ((tid & 7) * 16) ^ (((tid >> 3) & 7) << 4);
  const unsigned short* pV0 = Vt + ((size_t)hk * HD + (tid >> 3)) * S_LEN + (vcb >> 1);

  const int hsel = fq >> 1;
  const int srcA = fr + ((2 * (fq & 1)) << 4);
  const int srcB = fr + ((2 * (fq & 1) + 1) << 4);

  float l_acc = 0.f;
  floatx4 o[8] = {};

#define STAGE(buf, t)                                                           \
  do {                                                                          \
    const unsigned short* pk_ = pK0 + (size_t)(t) * 64 * HD;                    \
    const unsigned short* pv_ = pV0 + (t) * 64;                                 \
    _Pragma("unroll")                                                           \
    for (int j = 0; j < 2; ++j)                                                 \
      gld_lds16(pk_ + (size_t)j * 32 * HD, &Kl[buf][j * 4096 + w * 512]);       \
    _Pragma("unroll")                                                           \
    for (int j = 0; j < 2; ++j)                                                 \
      gld_lds16(pv_ + (size_t)j * 64 * S_LEN, &Vl[buf][j * 4096 + w * 512]);    \
  } while (0)

  STAGE(0, 0);
  asm volatile("s_waitcnt vmcnt(0)" ::: "memory");
  __syncthreads();

  const int nt = 2 * qt + 2;
  int cur = 0;
  for (int t = 0; t < nt; ++t) {
    const int kv0 = t * 64;
    if (t + 1 < nt) STAGE(cur ^ 1, t + 1);

    floatx4 St[4] = {};
    const unsigned short* Kc = &Kl[cur][0];
    const unsigned short* Vc = &Vl[cur][0];
    __builtin_amdgcn_s_setprio(1);
#pragma unroll
    for (int ks = 0; ks < 4; ++ks) {
#pragma unroll
      for (int n = 0; n < 4; ++n) {
        int row = n * 16 + fr;
        int cb = (ks * 64 + fq * 16) ^ ((row & 7) << 4);
        short8v kf = *(const short8v*)&Kc[row * 128 + (cb >> 1)];
        St[n] = __builtin_amdgcn_mfma_f32_16x16x32_bf16(kf, aq[ks], St[n], 0, 0, 0);
      }
    }
    __builtin_amdgcn_s_setprio(0);

    if (t >= 2 * qt) {
#pragma unroll
      for (int n = 0; n < 4; ++n) {
#pragma unroll
        for (int r = 0; r < 4; ++r) {
          int kvg = kv0 + n * 16 + fq * 4 + r;
          if (kvg > qb + w * 16 + fr) St[n][r] = -1e30f;
        }
      }
    }

    unsigned int pk[4][2];
#pragma unroll
    for (int n = 0; n < 4; ++n) {
      float p0 = exp2f(St[n][0]);
      float p1 = exp2f(St[n][1]);
      float p2 = exp2f(St[n][2]);
      float p3 = exp2f(St[n][3]);
      l_acc += (p0 + p1) + (p2 + p3);
      pk[n][0] = cvtpk_bf16(p0, p1);
      pk[n][1] = cvtpk_bf16(p2, p3);
    }

    short8v pa[2];
#pragma unroll
    for (int ks = 0; ks < 2; ++ks) {
      unsigned int v0a = __shfl(pk[2 * ks][0], srcA), v0b = __shfl(pk[2 * ks + 1][0], srcA);
      unsigned int v1a = __shfl(pk[2 * ks][1], srcA), v1b = __shfl(pk[2 * ks + 1][1], srcA);
      unsigned int v2a = __shfl(pk[2 * ks][0], srcB), v2b = __shfl(pk[2 * ks + 1][0], srcB);
      unsigned int v3a = __shfl(pk[2 * ks][1], srcB), v3b = __shfl(pk[2 * ks + 1][1], srcB);
      uint4 u;
      u.x = hsel ? v0b : v0a;
      u.y = hsel ? v1b : v1a;
      u.z = hsel ? v2b : v2a;
      u.w = hsel ? v3b : v3a;
      pa[ks] = *(short8v*)&u;
    }

    __builtin_amdgcn_s_setprio(1);
#pragma unroll
    for (int nf = 0; nf < 8; ++nf) {
#pragma unroll
      for (int ks = 0; ks < 2; ++ks) {
        int row = nf * 16 + fr;
        int cb = (ks * 64 + fq * 16) ^ ((row & 7) << 4);
        short8v bv = *(const short8v*)&Vc[row * 64 + (cb >> 1)];
        o[nf] = __builtin_amdgcn_mfma_f32_16x16x32_bf16(pa[ks], bv, o[nf], 0, 0, 0);
      }
    }
    __builtin_amdgcn_s_setprio(0);

    if (t + 1 < nt) {
      asm volatile("s_waitcnt vmcnt(0)" ::: "memory");
      __syncthreads();
      cur ^= 1;
    }
  }
#undef STAGE

  float L = l_acc;
  L += __shfl_xor(L, 16);
  L += __shfl_xor(L, 32);
  float rinv[4];
#pragma unroll
  for (int r = 0; r < 4; ++r) rinv[r] = 1.0f / __shfl(L, fq * 4 + r);

  unsigned short* aop = Ao + (size_t)(qb + w * 16 + fq * 4) * HID + h * HD + fr;
#pragma unroll
  for (int nf = 0; nf < 8; ++nf)
#pragma unroll
    for (int r = 0; r < 4; ++r)
      aop[(size_t)r * HID + nf * 16] = f2bf(o[nf][r] * rinv[r]);
}

// ---------------- launch ----------------
extern "C" void kernel_launch(void* const* d_in, const int* in_sizes, int n_in,
                              void* d_out, int out_size, void* d_ws, size_t ws_size,
                              hipStream_t stream) {
  (void)in_sizes; (void)n_in; (void)out_size; (void)ws_size;
  const float* X    = (const float*)d_in[0];
  const float* cosT = (const float*)d_in[3];
  const float* sinT = (const float*)d_in[4];
  const float* Wq   = (const float*)d_in[5];
  const float* Wk   = (const float*)d_in[6];
  const float* Wv   = (const float*)d_in[7];
  const float* Wo   = (const float*)d_in[8];

  char* ws = (char*)d_ws;
  size_t off = 0;
  auto alloc = [&](size_t bytes) { char* p = ws + off; off += (bytes + 255) & ~(size_t)255; return p; };
  unsigned short* Xb  = (unsigned short*)alloc((size_t)S_LEN * HID * 2);
  // Wqb/Wkb/Wvb contiguous -> concatenated B matrix [Wq;Wk;Wv] (6144x4096)
  unsigned short* Wqb = (unsigned short*)alloc((size_t)HID * HID * 2);
  unsigned short* Wkb = (unsigned short*)alloc((size_t)1024 * HID * 2);
  unsigned short* Wvb = (unsigned short*)alloc((size_t)1024 * HID * 2);
  unsigned short* Wob = (unsigned short*)alloc((size_t)HID * HID * 2);
  unsigned short* Qg  = (unsigned short*)alloc((size_t)S_LEN * HID * 2);
  unsigned short* Kg  = (unsigned short*)alloc((size_t)S_LEN * 1024 * 2);
  unsigned short* Vt  = (unsigned short*)alloc((size_t)1024 * S_LEN * 2);
  unsigned short* Kr = Wqb;      // alias: Wqb dead after gemm_qkv
  unsigned short* Ao = Xb;       // alias: Xb dead after gemm_qkv

  cvt_all<<<2048, 256, 0, stream>>>(X, Wq, Wk, Wv, Wo, Xb, Wqb, Wkb, Wvb, Wob);
  gemm_qkv<<<dim3(32, 8), 512, 0, stream>>>(Xb, Wqb, Qg, Kg, Vt);
  rope_k<<<(NKV * S_LEN * 64) / 256, 256, 0, stream>>>(Kg, cosT, sinT, Kr);
  attn_fwd<<<512, 512, 0, stream>>>(Qg, cosT, sinT, Kr, Vt, Ao);
  gemm_o<<<dim3(32, 8), 512, 0, stream>>>(Ao, Wob, (float*)d_out);
}

// Round 19
// 282.185 us; speedup vs baseline: 1.0660x; 1.0111x over previous
//
#include <hip/hip_runtime.h>
#include <hip/hip_bf16.h>

#define S_LEN 2048
#define HID   4096
#define NH    32
#define NKV   8
#define HD    128

typedef __attribute__((ext_vector_type(8))) short short8v;
typedef __attribute__((ext_vector_type(4))) float floatx4;

__device__ __forceinline__ float bf2f(unsigned short u) {
  union { unsigned int u32; float f; } v; v.u32 = ((unsigned int)u) << 16; return v.f;
}
__device__ __forceinline__ unsigned short f2bf(float f) {
  union { float f; unsigned int u; } v; v.f = f;
  unsigned int u = v.u + 0x7fffu + ((v.u >> 16) & 1u);
  return (unsigned short)(u >> 16);
}
__device__ __forceinline__ unsigned int cvtpk_bf16(float lo, float hi) {
  unsigned int r;
  asm("v_cvt_pk_bf16_f32 %0, %1, %2" : "=v"(r) : "v"(lo), "v"(hi));
  return r;
}

__device__ __forceinline__ void gld_lds16(const void* g, void* l) {
  __builtin_amdgcn_global_load_lds((const __attribute__((address_space(1))) void*)g,
                                   (__attribute__((address_space(3))) void*)l, 16, 0, 0);
}

// ---------------- fused f32 -> bf16 convert, 32B-read / 16B-write per iter ----
__global__ __launch_bounds__(256) void cvt_all(const float* __restrict__ X,  const float* __restrict__ Wq,
                                               const float* __restrict__ Wk, const float* __restrict__ Wv,
                                               const float* __restrict__ Wo,
                                               unsigned short* __restrict__ Xb,  unsigned short* __restrict__ Wqb,
                                               unsigned short* __restrict__ Wkb, unsigned short* __restrict__ Wvb,
                                               unsigned short* __restrict__ Wob) {
  const int c0 = 1048576;            // X  (float8 units)
  const int c1 = c0 + 2097152;       // Wq
  const int c2 = c1 + 524288;        // Wk
  const int c3 = c2 + 524288;        // Wv
  const int c4 = c3 + 2097152;       // Wo
  int i = blockIdx.x * blockDim.x + threadIdx.x;
  int stride = gridDim.x * blockDim.x;
  for (; i < c4; i += stride) {
    const float* src; unsigned short* dst; int off;
    if (i < c0)      { src = X;  dst = Xb;  off = i; }
    else if (i < c1) { src = Wq; dst = Wqb; off = i - c0; }
    else if (i < c2) { src = Wk; dst = Wkb; off = i - c1; }
    else if (i < c3) { src = Wv; dst = Wvb; off = i - c2; }
    else             { src = Wo; dst = Wob; off = i - c3; }
    float4 v0 = ((const float4*)src)[2 * off];
    float4 v1 = ((const float4*)src)[2 * off + 1];
    union { ushort4 h[2]; uint4 u; } o;
    o.h[0].x = f2bf(v0.x); o.h[0].y = f2bf(v0.y); o.h[0].z = f2bf(v0.z); o.h[0].w = f2bf(v0.w);
    o.h[1].x = f2bf(v1.x); o.h[1].y = f2bf(v1.y); o.h[1].z = f2bf(v1.z); o.h[1].w = f2bf(v1.w);
    ((uint4*)dst)[off] = o.u;
  }
}

// =====================================================================
// gemm_qkv: 256x192 over concatenated B = [Wq;Wk;Wv] (6144x4096).
// Grid (32,8) = 256 equal blocks. 512 thr = 8 waves (2M x 4N), acc[8][3].
// r18-style pipeline: A TRIPLE-buffered (3x32 KB), B DOUBLE-buffered
// (2x24 KB) = 144 KB LDS. ONE barrier per K-tile (was 2):
//   tile t: rd kh0 (8A+3B); stage B(t+1)->buf (t+1)&1, A(t+2)->buf (t+2)%3;
//           24-MFMA; rd kh1; 24-MFMA; vmcnt(4); barrier.
// Ledger (A=4 loads/tile, B=3, B issued before A): prologue A0,B0,A1 (11)
// -> vmcnt(4). Steady: enter 4 = A(t+1); +7 -> 11; vmcnt(4) retires exactly
// A(t+1)+B(t+1). t=NT-2 -> vmcnt(0); t=NT-1 none. Write-safety: staged bufs'
// last readers are tile t-1, barrier-protected.
// =====================================================================
__global__ __launch_bounds__(512, 2) void gemm_qkv(const unsigned short* __restrict__ Xb,
                                                   const unsigned short* __restrict__ Bcat,
                                                   unsigned short* __restrict__ Qg,
                                                   unsigned short* __restrict__ Kg,
                                                   unsigned short* __restrict__ Vt) {
  __shared__ unsigned short lds[73728];   // 144 KB: A 3*16384, B base 49152 + 2*12288
  const int K = 4096;
  const int tid = threadIdx.x;
  const int w = tid >> 6, lane = tid & 63;
  const int fr = lane & 15, fq = lane >> 4;
  const int wm = w >> 2, wn = w & 3;
  const int brow = blockIdx.y * 256, bcol = blockIdx.x * 192;

  const int r0s = w * 32 + (lane >> 2);
  const int r1s = r0s + 16;
  const int sl0 = ((lane & 3) ^ ((r0s >> 1) & 3)) << 3;
  const int sl1 = ((lane & 3) ^ ((r1s >> 1) & 3)) << 3;
  const unsigned short* pAs0 = Xb + (size_t)(brow + r0s) * K + sl0;
  const unsigned short* pAs1 = Xb + (size_t)(brow + r1s) * K + sl1;

  const unsigned short* pBs[3];
#pragma unroll
  for (int j = 0; j < 3; ++j) {
    int c = tid + j * 512;
    int khj = (c >= 768) ? 1 : 0;
    int rowj = (c - khj * 768) >> 2;
    int slotj = c & 3;
    pBs[j] = Bcat + (size_t)(bcol + rowj) * K + khj * 32 +
             ((slotj ^ ((rowj >> 1) & 3)) << 3);
  }

  const int sl = (fq ^ ((fr >> 1) & 3)) << 3;
  int aoffb[8], boffb[3];
#pragma unroll
  for (int m = 0; m < 8; ++m) aoffb[m] = (wm * 128 + m * 16 + fr) * 32 + sl;
#pragma unroll
  for (int n = 0; n < 3; ++n) boffb[n] = (wn * 48 + n * 16 + fr) * 32 + sl;

#define STG_A(buf, kh, t)                                                     \
  do {                                                                        \
    const int ko_ = (t) * 64 + (kh) * 32;                                     \
    gld_lds16(pAs0 + ko_, lds + (buf) * 16384 + (kh) * 8192 + w * 1024);      \
    gld_lds16(pAs1 + ko_, lds + (buf) * 16384 + (kh) * 8192 + w * 1024 + 512);\
  } while (0)
#define STG_B(buf, t)                                                         \
  do {                                                                        \
    const int ko_ = (t) * 64;                                                 \
    gld_lds16(pBs[0] + ko_, lds + 49152 + (buf) * 12288 + w * 512);           \
    gld_lds16(pBs[1] + ko_, lds + 49152 + (buf) * 12288 + 4096 + w * 512);    \
    gld_lds16(pBs[2] + ko_, lds + 49152 + (buf) * 12288 + 8192 + w * 512);    \
  } while (0)

  floatx4 acc[8][3] = {};

  // prologue: A(0), B(0), A(1)  (11 loads); wait A0+B0 (leave A1's 4)
  STG_A(0, 0, 0); STG_A(0, 1, 0);
  STG_B(0, 0);
  STG_A(1, 0, 1); STG_A(1, 1, 1);
  asm volatile("s_waitcnt vmcnt(4)" ::: "memory");
  __builtin_amdgcn_s_barrier();

  const int NT = K / 64;   // 64
  int ab = 0;              // t % 3
  for (int t = 0; t < NT; ++t) {
    const int bb = t & 1;
    const unsigned short* LA = lds + ab * 16384;
    const unsigned short* LB = lds + 49152 + bb * 12288;
    short8v a_[8], b_[3];

    // ---- kh0 reads ----
#pragma unroll
    for (int m = 0; m < 8; ++m) a_[m] = *(const short8v*)&LA[aoffb[m]];
#pragma unroll
    for (int n = 0; n < 3; ++n) b_[n] = *(const short8v*)&LB[boffb[n]];

    // stage next work: B(t+1) FIRST (ledger order), then A(t+2)
    if (t + 1 < NT) STG_B(bb ^ 1, t + 1);
    if (t + 2 < NT) {
      const int nb = (ab + 2 >= 3) ? ab - 1 : ab + 2;   // (t+2)%3
      STG_A(nb, 0, t + 2); STG_A(nb, 1, t + 2);
    }

    __builtin_amdgcn_s_setprio(1);
#pragma unroll
    for (int m = 0; m < 8; ++m)
#pragma unroll
      for (int n = 0; n < 3; ++n)
        acc[m][n] = __builtin_amdgcn_mfma_f32_16x16x32_bf16(a_[m], b_[n], acc[m][n], 0, 0, 0);
    __builtin_amdgcn_s_setprio(0);

    // ---- kh1 reads + MFMA (same buffers; no barrier needed between) ----
#pragma unroll
    for (int m = 0; m < 8; ++m) a_[m] = *(const short8v*)&LA[8192 + aoffb[m]];
#pragma unroll
    for (int n = 0; n < 3; ++n) b_[n] = *(const short8v*)&LB[6144 + boffb[n]];
    __builtin_amdgcn_s_setprio(1);
#pragma unroll
    for (int m = 0; m < 8; ++m)
#pragma unroll
      for (int n = 0; n < 3; ++n)
        acc[m][n] = __builtin_amdgcn_mfma_f32_16x16x32_bf16(a_[m], b_[n], acc[m][n], 0, 0, 0);
    __builtin_amdgcn_s_setprio(0);

    if (t + 2 < NT)      asm volatile("s_waitcnt vmcnt(4)" ::: "memory");  // A(t+1)+B(t+1) in
    else if (t + 1 < NT) asm volatile("s_waitcnt vmcnt(0)" ::: "memory");  // drain last
    if (t + 1 < NT) __builtin_amdgcn_s_barrier();
    ab = (ab == 2) ? 0 : ab + 1;
  }
#undef STG_A
#undef STG_B

  // ---- epilogue: per-frag routing (boundaries 4096/5120 are 16-aligned) ----
  const int r0 = brow + wm * 128 + fq * 4;
#pragma unroll
  for (int m = 0; m < 8; ++m)
#pragma unroll
    for (int n = 0; n < 3; ++n) {
      const int bc = bcol + wn * 48 + n * 16;   // frag base col (wave-uniform)
      if (bc < 4096) {
#pragma unroll
        for (int r = 0; r < 4; ++r)
          Qg[(size_t)(r0 + m * 16 + r) * HID + bc + fr] = f2bf(acc[m][n][r]);
      } else if (bc < 5120) {
#pragma unroll
        for (int r = 0; r < 4; ++r)
          Kg[(size_t)(r0 + m * 16 + r) * 1024 + bc - 4096 + fr] = f2bf(acc[m][n][r]);
      } else {
        ushort4 pk;
        pk.x = f2bf(acc[m][n][0]); pk.y = f2bf(acc[m][n][1]);
        pk.z = f2bf(acc[m][n][2]); pk.w = f2bf(acc[m][n][3]);
        *(ushort4*)&Vt[(size_t)(bc - 5120 + fr) * S_LEN + (r0 + m * 16)] = pk;
      }
    }
}

// =====================================================================
// gemm_o: 256x128 / TRIPLE-BUFFERED single-phase-per-tile (r18 proven).
// =====================================================================
__global__ __launch_bounds__(512, 2) void gemm_o(const unsigned short* __restrict__ Ao,
                                                 const unsigned short* __restrict__ Wob,
                                                 float* __restrict__ Out) {
  __shared__ unsigned short lds[73728];   // 144 KB: A 3*16384, B base 49152 + 3*8192
  const int K = 4096;
  const int tid = threadIdx.x;
  const int w = tid >> 6, lane = tid & 63;
  const int fr = lane & 15, fq = lane >> 4;
  const int wm = w >> 1, wn = w & 1;
  const int brow = blockIdx.y * 256, bcol = blockIdx.x * 128;

  const int rA = tid >> 2;
  const int sA = ((tid & 3) ^ ((rA >> 1) & 3)) << 3;
  const unsigned short* pA0 = Ao  + (size_t)(brow + rA) * K + sA;
  const unsigned short* pA1 = Ao  + (size_t)(brow + 128 + rA) * K + sA;
  const unsigned short* pB0 = Wob + (size_t)(bcol + rA) * K + sA;

  const int sl = (fq ^ ((fr >> 1) & 3)) << 3;
  int aoff[4], boff[4];
#pragma unroll
  for (int m = 0; m < 4; ++m) aoff[m] = (wm * 64 + m * 16 + fr) * 32 + sl;
#pragma unroll
  for (int n = 0; n < 4; ++n) boff[n] = (wn * 64 + n * 16 + fr) * 32 + sl;

  floatx4 acc[4][4] = {};

#define STG_KH(buf, kh, t)                                                       \
  do {                                                                           \
    const int ko_ = (t) * 64 + (kh) * 32;                                        \
    gld_lds16(pA0 + ko_, lds + (buf) * 16384 + (kh) * 8192 + w * 512);           \
    gld_lds16(pA1 + ko_, lds + (buf) * 16384 + (kh) * 8192 + 4096 + w * 512);    \
    gld_lds16(pB0 + ko_, lds + 49152 + (buf) * 8192 + (kh) * 4096 + w * 512);    \
  } while (0)

  STG_KH(0, 0, 0); STG_KH(0, 1, 0);
  STG_KH(1, 0, 1); STG_KH(1, 1, 1);
  asm volatile("s_waitcnt vmcnt(6)" ::: "memory");
  __builtin_amdgcn_s_barrier();

  const int NT = K / 64;   // 64
  int a3 = 0;
  for (int t = 0; t < NT; ++t) {
    const unsigned short* LA = lds + a3 * 16384;
    const unsigned short* LB = lds + 49152 + a3 * 8192;
    short8v a0_[4], b0_[4], a1_[4], b1_[4];

#pragma unroll
    for (int m = 0; m < 4; ++m) a0_[m] = *(const short8v*)&LA[aoff[m]];
#pragma unroll
    for (int n = 0; n < 4; ++n) b0_[n] = *(const short8v*)&LB[boff[n]];
#pragma unroll
    for (int m = 0; m < 4; ++m) a1_[m] = *(const short8v*)&LA[8192 + aoff[m]];
#pragma unroll
    for (int n = 0; n < 4; ++n) b1_[n] = *(const short8v*)&LB[4096 + boff[n]];

    if (t + 2 < NT) {
      const int nb = (a3 + 2 >= 3) ? a3 - 1 : a3 + 2;
      STG_KH(nb, 0, t + 2);
      STG_KH(nb, 1, t + 2);
    }

    __builtin_amdgcn_s_setprio(1);
#pragma unroll
    for (int m = 0; m < 4; ++m)
#pragma unroll
      for (int n = 0; n < 4; ++n)
        acc[m][n] = __builtin_amdgcn_mfma_f32_16x16x32_bf16(a0_[m], b0_[n], acc[m][n], 0, 0, 0);
#pragma unroll
    for (int m = 0; m < 4; ++m)
#pragma unroll
      for (int n = 0; n < 4; ++n)
        acc[m][n] = __builtin_amdgcn_mfma_f32_16x16x32_bf16(a1_[m], b1_[n], acc[m][n], 0, 0, 0);
    __builtin_amdgcn_s_setprio(0);

    if (t + 2 < NT)      asm volatile("s_waitcnt vmcnt(6)" ::: "memory");
    else if (t + 1 < NT) asm volatile("s_waitcnt vmcnt(0)" ::: "memory");
    if (t + 1 < NT) __builtin_amdgcn_s_barrier();
    a3 = (a3 == 2) ? 0 : a3 + 1;
  }
#undef STG_KH

  const int r0 = brow + wm * 64 + fq * 4;
  const int c0 = bcol + wn * 64 + fr;
#pragma unroll
  for (int m = 0; m < 4; ++m)
#pragma unroll
    for (int n = 0; n < 4; ++n)
#pragma unroll
      for (int r = 0; r < 4; ++r)
        Out[(size_t)(r0 + m * 16 + r) * HID + c0 + n * 16] = acc[m][n][r];
}

// ---------------- K RoPE: INTERLEAVED layout (pair results at 2j, 2j+1) ------
__global__ __launch_bounds__(256) void rope_k(const unsigned short* __restrict__ In,
                                              const float* __restrict__ cosT,
                                              const float* __restrict__ sinT,
                                              unsigned short* __restrict__ Out) {
  int idx = blockIdx.x * 256 + threadIdx.x;
  int j = idx & 63;
  int s = (idx >> 6) & (S_LEN - 1);
  int h = idx >> 17;
  unsigned int pr = *(const unsigned int*)(In + (size_t)s * (NKV * HD) + h * HD + 2 * j);
  float k1 = bf2f((unsigned short)(pr & 0xffffu));
  float k2 = bf2f((unsigned short)(pr >> 16));
  float c = cosT[s * 64 + j], sn = sinT[s * 64 + j];
  unsigned int pk = (unsigned int)f2bf(k1 * c - k2 * sn) |
                    ((unsigned int)f2bf(k2 * c + k1 * sn) << 16);
  *(unsigned int*)(Out + ((size_t)h * S_LEN + s) * HD + 2 * j) = pk;
}

// ---------------- Flash attention: 8-wave blocks, shared K/V tile (r12, proven)
__global__ __launch_bounds__(512, 4) void attn_fwd(const unsigned short* __restrict__ Qg,
                                                   const float* __restrict__ cosT,
                                                   const float* __restrict__ sinT,
                                                   const unsigned short* __restrict__ Kr,
                                                   const unsigned short* __restrict__ Vt,
                                                   unsigned short* __restrict__ Ao) {
  __shared__ unsigned short Kl[2][64 * 128];   // [kv][128], swizzled (cb ^ (row&7)<<4)
  __shared__ unsigned short Vl[2][128 * 64];   // [d][kv], swizzled
  const int id = blockIdx.x;
  const int xcd = id & 7, rr = id >> 3;
  const int qt = 15 - (rr >> 2);               // heavy first
  const int h  = xcd * 4 + (rr & 3);           // XCD c <-> kv-head c
  const int hk = h >> 2;
  const int qb = qt * 128;
  const int tid = threadIdx.x, w = tid >> 6, lane = tid & 63;
  const int fr = lane & 15, fq = lane >> 4;

  short8v aq[4];
  {
    const int s_row = qb + w * 16 + fr;
    const unsigned short* qp = Qg + (size_t)s_row * HID + h * HD + fq * 8;
    const float* cb = cosT + s_row * 64;
    const float* sb = sinT + s_row * 64;
    const float SC = 0.12751744f;   // log2(e)/sqrt(128)
#pragma unroll
    for (int ks = 0; ks < 4; ++ks) {
      short8v raw = *(const short8v*)(qp + ks * 32);
      short8v ov;
#pragma unroll
      for (int e = 0; e < 4; ++e) {
        float q1 = bf2f((unsigned short)raw[2 * e]);
        float q2 = bf2f((unsigned short)raw[2 * e + 1]);
        int j = ks * 16 + fq * 4 + e;
        float c = cb[j], sn = sb[j];
        ov[2 * e]     = (short)f2bf(SC * (q1 * c - q2 * sn));
        ov[2 * e + 1] = (short)f2bf(SC * (q2 * c + q1 * sn));
      }
      aq[ks] = ov;
    }
  }

  const int kcb = ((tid & 15) * 16) ^ (((tid >> 4) & 7) << 4);
  const unsigned short* pK0 = Kr + ((size_t)hk * S_LEN + (tid >> 4)) * HD + (kcb >> 1);
  const int vcb = ((tid & 7) * 16) ^ (((tid >> 3) & 7) << 4);
  const unsigned short* pV0 = Vt + ((size_t)hk * HD + (tid >> 3)) * S_LEN + (vcb >> 1);

  const int hsel = fq >> 1;
  const int srcA = fr + ((2 * (fq & 1)) << 4);
  const int srcB = fr + ((2 * (fq & 1) + 1) << 4);

  float l_acc = 0.f;
  floatx4 o[8] = {};

#define STAGE(buf, t)                                                           \
  do {                                                                          \
    const unsigned short* pk_ = pK0 + (size_t)(t) * 64 * HD;                    \
    const unsigned short* pv_ = pV0 + (t) * 64;                                 \
    _Pragma("unroll")                                                           \
    for (int j = 0; j < 2; ++j)                                                 \
      gld_lds16(pk_ + (size_t)j * 32 * HD, &Kl[buf][j * 4096 + w * 512]);       \
    _Pragma("unroll")                                                           \
    for (int j = 0; j < 2; ++j)                                                 \
      gld_lds16(pv_ + (size_t)j * 64 * S_LEN, &Vl[buf][j * 4096 + w * 512]);    \
  } while (0)

  STAGE(0, 0);
  asm volatile("s_waitcnt vmcnt(0)" ::: "memory");
  __syncthreads();

  const int nt = 2 * qt + 2;
  int cur = 0;
  for (int t = 0; t < nt; ++t) {
    const int kv0 = t * 64;
    if (t + 1 < nt) STAGE(cur ^ 1, t + 1);

    floatx4 St[4] = {};
    const unsigned short* Kc = &Kl[cur][0];
    const unsigned short* Vc = &Vl[cur][0];
    __builtin_amdgcn_s_setprio(1);
#pragma unroll
    for (int ks = 0; ks < 4; ++ks) {
#pragma unroll
      for (int n = 0; n < 4; ++n) {
        int row = n * 16 + fr;
        int cb = (ks * 64 + fq * 16) ^ ((row & 7) << 4);
        short8v kf = *(const short8v*)&Kc[row * 128 + (cb >> 1)];
        St[n] = __builtin_amdgcn_mfma_f32_16x16x32_bf16(kf, aq[ks], St[n], 0, 0, 0);
      }
    }
    __builtin_amdgcn_s_setprio(0);

    if (t >= 2 * qt) {
#pragma unroll
      for (int n = 0; n < 4; ++n) {
#pragma unroll
        for (int r = 0; r < 4; ++r) {
          int kvg = kv0 + n * 16 + fq * 4 + r;
          if (kvg > qb + w * 16 + fr) St[n][r] = -1e30f;
        }
      }
    }

    unsigned int pk[4][2];
#pragma unroll
    for (int n = 0; n < 4; ++n) {
      float p0 = exp2f(St[n][0]);
      float p1 = exp2f(St[n][1]);
      float p2 = exp2f(St[n][2]);
      float p3 = exp2f(St[n][3]);
      l_acc += (p0 + p1) + (p2 + p3);
      pk[n][0] = cvtpk_bf16(p0, p1);
      pk[n][1] = cvtpk_bf16(p2, p3);
    }

    short8v pa[2];
#pragma unroll
    for (int ks = 0; ks < 2; ++ks) {
      unsigned int v0a = __shfl(pk[2 * ks][0], srcA), v0b = __shfl(pk[2 * ks + 1][0], srcA);
      unsigned int v1a = __shfl(pk[2 * ks][1], srcA), v1b = __shfl(pk[2 * ks + 1][1], srcA);
      unsigned int v2a = __shfl(pk[2 * ks][0], srcB), v2b = __shfl(pk[2 * ks + 1][0], srcB);
      unsigned int v3a = __shfl(pk[2 * ks][1], srcB), v3b = __shfl(pk[2 * ks + 1][1], srcB);
      uint4 u;
      u.x = hsel ? v0b : v0a;
      u.y = hsel ? v1b : v1a;
      u.z = hsel ? v2b : v2a;
      u.w = hsel ? v3b : v3a;
      pa[ks] = *(short8v*)&u;
    }

    __builtin_amdgcn_s_setprio(1);
#pragma unroll
    for (int nf = 0; nf < 8; ++nf) {
#pragma unroll
      for (int ks = 0; ks < 2; ++ks) {
        int row = nf * 16 + fr;
        int cb = (ks * 64 + fq * 16) ^ ((row & 7) << 4);
        short8v bv = *(const short8v*)&Vc[row * 64 + (cb >> 1)];
        o[nf] = __builtin_amdgcn_mfma_f32_16x16x32_bf16(pa[ks], bv, o[nf], 0, 0, 0);
      }
    }
    __builtin_amdgcn_s_setprio(0);

    if (t + 1 < nt) {
      asm volatile("s_waitcnt vmcnt(0)" ::: "memory");
      __syncthreads();
      cur ^= 1;
    }
  }
#undef STAGE

  float L = l_acc;
  L += __shfl_xor(L, 16);
  L += __shfl_xor(L, 32);
  float rinv[4];
#pragma unroll
  for (int r = 0; r < 4; ++r) rinv[r] = 1.0f / __shfl(L, fq * 4 + r);

  unsigned short* aop = Ao + (size_t)(qb + w * 16 + fq * 4) * HID + h * HD + fr;
#pragma unroll
  for (int nf = 0; nf < 8; ++nf)
#pragma unroll
    for (int r = 0; r < 4; ++r)
      aop[(size_t)r * HID + nf * 16] = f2bf(o[nf][r] * rinv[r]);
}

// ---------------- launch ----------------
extern "C" void kernel_launch(void* const* d_in, const int* in_sizes, int n_in,
                              void* d_out, int out_size, void* d_ws, size_t ws_size,
                              hipStream_t stream) {
  (void)in_sizes; (void)n_in; (void)out_size; (void)ws_size;
  const float* X    = (const float*)d_in[0];
  const float* cosT = (const float*)d_in[3];
  const float* sinT = (const float*)d_in[4];
  const float* Wq   = (const float*)d_in[5];
  const float* Wk   = (const float*)d_in[6];
  const float* Wv   = (const float*)d_in[7];
  const float* Wo   = (const float*)d_in[8];

  char* ws = (char*)d_ws;
  size_t off = 0;
  auto alloc = [&](size_t bytes) { char* p = ws + off; off += (bytes + 255) & ~(size_t)255; return p; };
  unsigned short* Xb  = (unsigned short*)alloc((size_t)S_LEN * HID * 2);
  // Wqb/Wkb/Wvb contiguous -> concatenated B matrix [Wq;Wk;Wv] (6144x4096)
  unsigned short* Wqb = (unsigned short*)alloc((size_t)HID * HID * 2);
  unsigned short* Wkb = (unsigned short*)alloc((size_t)1024 * HID * 2);
  unsigned short* Wvb = (unsigned short*)alloc((size_t)1024 * HID * 2);
  unsigned short* Wob = (unsigned short*)alloc((size_t)HID * HID * 2);
  unsigned short* Qg  = (unsigned short*)alloc((size_t)S_LEN * HID * 2);
  unsigned short* Kg  = (unsigned short*)alloc((size_t)S_LEN * 1024 * 2);
  unsigned short* Vt  = (unsigned short*)alloc((size_t)1024 * S_LEN * 2);
  unsigned short* Kr = Wqb;      // alias: Wqb dead after gemm_qkv
  unsigned short* Ao = Xb;       // alias: Xb dead after gemm_qkv

  cvt_all<<<2048, 256, 0, stream>>>(X, Wq, Wk, Wv, Wo, Xb, Wqb, Wkb, Wvb, Wob);
  gemm_qkv<<<dim3(32, 8), 512, 0, stream>>>(Xb, Wqb, Qg, Kg, Vt);
  rope_k<<<(NKV * S_LEN * 64) / 256, 256, 0, stream>>>(Kg, cosT, sinT, Kr);
  attn_fwd<<<512, 512, 0, stream>>>(Qg, cosT, sinT, Kr, Vt, Ao);
  gemm_o<<<dim3(32, 8), 512, 0, stream>>>(Ao, Wob, (float*)d_out);
}